// Round 1
// baseline (1241.297 us; speedup 1.0000x reference)
//
#include <hip/hip_runtime.h>
#include <math.h>

#define D 512
#define NT 3
#define KC 10

// ---------- helpers ----------

__device__ __forceinline__ unsigned encf(float f){
  unsigned u = __float_as_uint(f);
  return (u & 0x80000000u) ? ~u : (u | 0x80000000u);
}
__device__ __forceinline__ float decf(unsigned u){
  return (u & 0x80000000u) ? __uint_as_float(u & 0x7fffffffu)
                           : __uint_as_float(~u);
}
__device__ __forceinline__ float leaky(float x){ return x > 0.f ? x : 0.2f * x; }

// block reduce for 256-thread blocks (4 waves of 64)
__device__ __forceinline__ float4 bsum4(float4 v, float* lds /*>=16 floats*/){
  for (int o = 32; o > 0; o >>= 1){
    v.x += __shfl_down(v.x, o);
    v.y += __shfl_down(v.y, o);
    v.z += __shfl_down(v.z, o);
    v.w += __shfl_down(v.w, o);
  }
  int w = threadIdx.x >> 6, l = threadIdx.x & 63;
  if (l == 0){ lds[w*4+0]=v.x; lds[w*4+1]=v.y; lds[w*4+2]=v.z; lds[w*4+3]=v.w; }
  __syncthreads();
  float4 r;
  r.x = lds[0]+lds[4]+lds[8]+lds[12];
  r.y = lds[1]+lds[5]+lds[9]+lds[13];
  r.z = lds[2]+lds[6]+lds[10]+lds[14];
  r.w = lds[3]+lds[7]+lds[11]+lds[15];
  __syncthreads();
  return r;
}

// ---------- kernels ----------

// LayerNorm row-per-block (512 elems, 256 threads)
__launch_bounds__(256) __global__
void ln_kernel(const float* __restrict__ x, const float* __restrict__ g,
               const float* __restrict__ b, float* __restrict__ out, int N){
  __shared__ float lds[16];
  int n = blockIdx.x, tid = threadIdx.x;
  float v0 = x[(size_t)n*D + tid], v1 = x[(size_t)n*D + tid + 256];
  float4 s = bsum4(make_float4(v0+v1, v0*v0+v1*v1, 0.f, 0.f), lds);
  float mu = s.x * (1.f/D);
  float var = s.y * (1.f/D) - mu*mu;
  float r = rsqrtf(var + 1e-5f);
  out[(size_t)n*D + tid]       = (v0-mu)*r*g[tid]       + b[tid];
  out[(size_t)n*D + tid + 256] = (v1-mu)*r*g[tid+256]   + b[tid+256];
}

// f32 SGEMM C[M,512] = A[M,512] @ W[512,512] + bias (64x64 tile, BK=16, 4x4/thread)
__launch_bounds__(256) __global__
void gemm_bias(const float* __restrict__ A, const float* __restrict__ W,
               const float* __restrict__ bias, float* __restrict__ C, int M){
  __shared__ float As[16][64];
  __shared__ float Bs[16][64];
  int tid = threadIdx.x;
  int tx = tid & 15, ty = tid >> 4;
  int row0 = blockIdx.x * 64, col0 = blockIdx.y * 64;
  int aRow = tid >> 2, aK = (tid & 3) << 2;
  int bK = tid >> 4, bCol = (tid & 15) << 2;
  float acc[4][4] = {};
  for (int k0 = 0; k0 < D; k0 += 16){
    float4 av = make_float4(0.f,0.f,0.f,0.f);
    int ar = row0 + aRow;
    if (ar < M) av = *(const float4*)(A + (size_t)ar*D + k0 + aK);
    As[aK+0][aRow] = av.x; As[aK+1][aRow] = av.y;
    As[aK+2][aRow] = av.z; As[aK+3][aRow] = av.w;
    float4 bv = *(const float4*)(W + (size_t)(k0+bK)*D + col0 + bCol);
    *(float4*)(&Bs[bK][bCol]) = bv;
    __syncthreads();
    #pragma unroll
    for (int k = 0; k < 16; ++k){
      float4 a = *(const float4*)(&As[k][ty<<2]);
      float4 b = *(const float4*)(&Bs[k][tx<<2]);
      float ax[4] = {a.x,a.y,a.z,a.w}, bx[4] = {b.x,b.y,b.z,b.w};
      #pragma unroll
      for (int i = 0; i < 4; ++i)
        #pragma unroll
        for (int j = 0; j < 4; ++j)
          acc[i][j] += ax[i]*bx[j];
    }
    __syncthreads();
  }
  #pragma unroll
  for (int i = 0; i < 4; ++i){
    int r = row0 + (ty<<2) + i;
    if (r < M){
      int c = col0 + (tx<<2);
      float4 o = make_float4(acc[i][0]+bias[c], acc[i][1]+bias[c+1],
                             acc[i][2]+bias[c+2], acc[i][3]+bias[c+3]);
      *(float4*)(C + (size_t)r*D + c) = o;
    }
  }
}

// per-row dots of h1 with a_src, a_dst, t_dst
__launch_bounds__(256) __global__
void rowdots(const float* __restrict__ h1, const float* __restrict__ a_src,
             const float* __restrict__ a_dst, const float* __restrict__ t_dst,
             float* __restrict__ hs, float* __restrict__ hd, float* __restrict__ ht,
             int N){
  __shared__ float lds[16];
  int n = blockIdx.x, tid = threadIdx.x;
  float v0 = h1[(size_t)n*D + tid], v1 = h1[(size_t)n*D + tid + 256];
  float4 s = bsum4(make_float4(v0*a_src[tid] + v1*a_src[tid+256],
                               v0*a_dst[tid] + v1*a_dst[tid+256],
                               v0*t_dst[tid] + v1*t_dst[tid+256], 0.f), lds);
  if (tid == 0){ hs[n] = s.x; hd[n] = s.y; ht[n] = s.z; }
}

__launch_bounds__(256) __global__
void pnorm_kernel(const float* __restrict__ p, float* __restrict__ pn){
  __shared__ float lds[16];
  int tid = threadIdx.x;
  float v0 = p[tid], v1 = p[tid+256];
  float4 s = bsum4(make_float4(v0*v0 + v1*v1, 0.f, 0.f, 0.f), lds);
  if (tid == 0) pn[0] = sqrtf(s.x);
}

// per-edge: logit, seg id, segment max (ordered-uint atomicMax), segment count
__launch_bounds__(256) __global__
void edge_logit(const int* __restrict__ src, const int* __restrict__ dst,
                const int* __restrict__ ntype,
                const float* __restrict__ hd, const float* __restrict__ hs,
                float* __restrict__ logit, int* __restrict__ seg,
                unsigned* __restrict__ segmax, int* __restrict__ cnt, int E){
  int e = blockIdx.x*256 + threadIdx.x;
  if (e >= E) return;
  int s = src[e], d = dst[e];
  float l = leaky(hd[d] + hs[s]);
  int sg = d*NT + ntype[s];
  logit[e] = l;
  seg[e] = sg;
  atomicMax(&segmax[sg], encf(l));
  atomicAdd(&cnt[sg], 1);
}

// per-edge: w = exp(logit - segmax), segment sum (logit buffer overwritten in place)
__launch_bounds__(256) __global__
void edge_exp(float* __restrict__ logit_w, const int* __restrict__ seg,
              const unsigned* __restrict__ segmax, float* __restrict__ segsum, int E){
  int e = blockIdx.x*256 + threadIdx.x;
  if (e >= E) return;
  int sg = seg[e];
  float w = expf(logit_w[e] - decf(segmax[sg]));
  logit_w[e] = w;
  atomicAdd(&segsum[sg], w);
}

// single-block exclusive scan of cnt[n] -> offs[n]
__launch_bounds__(1024) __global__
void scan_excl(const int* __restrict__ cnt, int* __restrict__ offs, int n){
  __shared__ int buf[1024];
  __shared__ int carry;
  int tid = threadIdx.x;
  if (tid == 0) carry = 0;
  __syncthreads();
  for (int base = 0; base < n; base += 1024){
    int i = base + tid;
    int v = (i < n) ? cnt[i] : 0;
    buf[tid] = v;
    __syncthreads();
    for (int o = 1; o < 1024; o <<= 1){
      int t = (tid >= o) ? buf[tid - o] : 0;
      __syncthreads();
      buf[tid] += t;
      __syncthreads();
    }
    int incl = buf[tid];
    int c = carry;
    if (i < n) offs[i] = c + incl - v;
    __syncthreads();
    if (tid == 1023) carry = c + buf[1023];
    __syncthreads();
  }
}

// counting-sort scatter: edge ids grouped by seg
__launch_bounds__(256) __global__
void scatter_k(const int* __restrict__ seg, const int* __restrict__ offs,
               int* __restrict__ cursor, int* __restrict__ sorted, int E){
  int e = blockIdx.x*256 + threadIdx.x;
  if (e >= E) return;
  int sg = seg[e];
  int p = atomicAdd(&cursor[sg], 1);
  sorted[offs[sg] + p] = e;
}

// per node: aggregate messages for all 3 resolutions, beta softmax combine,
// LayerNorm, score = sigmoid(h2 . p/||p||). Writes h2 and score.
__launch_bounds__(256) __global__
void node_combine(const float* __restrict__ h1, const float* __restrict__ wbuf,
                  const int* __restrict__ sorted, const int* __restrict__ offs,
                  const int* __restrict__ cnt, const float* __restrict__ segsum,
                  const int* __restrict__ srcA,
                  const float* __restrict__ ht, const float* __restrict__ t_src,
                  const float* __restrict__ gamma, const float* __restrict__ beta,
                  const float* __restrict__ p, const float* __restrict__ pn,
                  float* __restrict__ h2, float* __restrict__ score, int N){
  __shared__ float lds[16];
  int n = blockIdx.x, tid = threadIdx.x;
  int i0 = tid, i1 = tid + 256;
  float acc[NT][2] = {};
  int c[NT];
  #pragma unroll
  for (int t = 0; t < NT; ++t){
    int sg = n*NT + t;
    c[t] = cnt[sg];
    if (c[t] > 0){
      float inv = 1.f / (segsum[sg] + 1e-16f);
      int beg = offs[sg];
      for (int k = 0; k < c[t]; ++k){
        int e = sorted[beg + k];
        float a = wbuf[e] * inv;
        const float* hr = h1 + (size_t)srcA[e]*D;
        acc[t][0] += a * hr[i0];
        acc[t][1] += a * hr[i1];
      }
    }
  }
  float ts0 = t_src[i0], ts1 = t_src[i1];
  float4 dt = bsum4(make_float4(acc[0][0]*ts0 + acc[0][1]*ts1,
                                acc[1][0]*ts0 + acc[1][1]*ts1,
                                acc[2][0]*ts0 + acc[2][1]*ts1, 0.f), lds);
  float htn = ht[n];
  float bl0 = c[0] > 0 ? leaky(htn + dt.x) : -1e9f;
  float bl1 = c[1] > 0 ? leaky(htn + dt.y) : -1e9f;
  float bl2 = c[2] > 0 ? leaky(htn + dt.z) : -1e9f;
  float mx = fmaxf(bl0, fmaxf(bl1, bl2));
  float e0 = expf(bl0 - mx), e1 = expf(bl1 - mx), e2 = expf(bl2 - mx);
  float invs = 1.f / (e0 + e1 + e2);
  float o0 = (e0*acc[0][0] + e1*acc[1][0] + e2*acc[2][0]) * invs;
  float o1 = (e0*acc[0][1] + e1*acc[1][1] + e2*acc[2][1]) * invs;
  // LayerNorm of combined row
  float4 s2 = bsum4(make_float4(o0 + o1, o0*o0 + o1*o1, 0.f, 0.f), lds);
  float mu = s2.x * (1.f/D);
  float var = s2.y * (1.f/D) - mu*mu;
  float r = rsqrtf(var + 1e-5f);
  float g0 = (o0 - mu)*r*gamma[i0] + beta[i0];
  float g1 = (o1 - mu)*r*gamma[i1] + beta[i1];
  h2[(size_t)n*D + i0] = g0;
  h2[(size_t)n*D + i1] = g1;
  float4 s3 = bsum4(make_float4(g0*p[i0] + g1*p[i1], 0.f, 0.f, 0.f), lds);
  if (tid == 0){
    float z = s3.x / (pn[0] + 1e-6f);
    score[n] = 1.f / (1.f + expf(-z));
  }
}

// iterative exact top-10 (ties -> lower index, matching jax.lax.top_k)
__launch_bounds__(1024) __global__
void topk_kernel(const float* __restrict__ score, const float* __restrict__ xy,
                 int* __restrict__ centers, float* __restrict__ cpos, int N){
  __shared__ float wv[16];
  __shared__ int wi[16];
  __shared__ int chosen[KC];
  int tid = threadIdx.x;
  for (int it = 0; it < KC; ++it){
    float bv = -INFINITY; int bi = 0x7fffffff;
    for (int i = tid; i < N; i += 1024){
      bool skip = false;
      for (int t = 0; t < it; ++t) if (chosen[t] == i) skip = true;
      if (skip) continue;
      float v = score[i];
      if (v > bv || (v == bv && i < bi)){ bv = v; bi = i; }
    }
    for (int o = 32; o > 0; o >>= 1){
      float ov = __shfl_down(bv, o);
      int oi = __shfl_down(bi, o);
      if (ov > bv || (ov == bv && oi < bi)){ bv = ov; bi = oi; }
    }
    if ((tid & 63) == 0){ wv[tid>>6] = bv; wi[tid>>6] = bi; }
    __syncthreads();
    if (tid == 0){
      float b = wv[0]; int bidx = wi[0];
      for (int w = 1; w < 16; ++w)
        if (wv[w] > b || (wv[w] == b && wi[w] < bidx)){ b = wv[w]; bidx = wi[w]; }
      chosen[it] = bidx;
      centers[it] = bidx;
      cpos[it*2+0] = xy[(size_t)bidx*2+0]*2.f - 1.f;
      cpos[it*2+1] = xy[(size_t)bidx*2+1]*2.f - 1.f;
    }
    __syncthreads();
  }
}

// nearest-center assignment + score-gated pooling, LDS partials then global atomics
__launch_bounds__(256) __global__
void pool_kernel(const float* __restrict__ h2, const float* __restrict__ score,
                 const float* __restrict__ xy, const float* __restrict__ cpos,
                 float* __restrict__ xsum, float* __restrict__ denom, int N){
  __shared__ float accs[KC][D];   // 20 KB
  __shared__ float dsum[KC];
  __shared__ float cp[KC*2];
  int tid = threadIdx.x;
  for (int i = tid; i < KC*D; i += 256) ((float*)accs)[i] = 0.f;
  if (tid < KC) dsum[tid] = 0.f;
  if (tid < KC*2) cp[tid] = cpos[tid];
  __syncthreads();
  for (int n = blockIdx.x; n < N; n += gridDim.x){
    float px = xy[(size_t)n*2+0]*2.f - 1.f;
    float py = xy[(size_t)n*2+1]*2.f - 1.f;
    int best = 0; float bd = 3.4e38f;
    #pragma unroll
    for (int k = 0; k < KC; ++k){
      float dx = px - cp[k*2], dy = py - cp[k*2+1];
      float d2v = dx*dx + dy*dy;
      if (d2v < bd){ bd = d2v; best = k; }
    }
    float s = score[n];
    accs[best][tid]       += s * h2[(size_t)n*D + tid];
    accs[best][tid + 256] += s * h2[(size_t)n*D + tid + 256];
    if (tid == 0) dsum[best] += s;
  }
  __syncthreads();
  for (int i = tid; i < KC*D; i += 256) atomicAdd(&xsum[i], ((float*)accs)[i]);
  if (tid < KC) atomicAdd(&denom[tid], dsum[tid]);
}

__launch_bounds__(256) __global__
void fin_kernel(const float* __restrict__ xsum, const float* __restrict__ denom,
                float* __restrict__ out){
  int k = blockIdx.x, tid = threadIdx.x;
  float inv = 1.f / (denom[k] + 1e-6f);
  out[(size_t)k*D + tid]       = xsum[(size_t)k*D + tid] * inv;
  out[(size_t)k*D + tid + 256] = xsum[(size_t)k*D + tid + 256] * inv;
}

// ---------- launch ----------

extern "C" void kernel_launch(void* const* d_in, const int* in_sizes, int n_in,
                              void* d_out, int out_size, void* d_ws, size_t ws_size,
                              hipStream_t stream){
  const float* x     = (const float*)d_in[0];
  const int*   ei    = (const int*)d_in[1];
  const int*   ntype = (const int*)d_in[2];
  // d_in[3] = tree (unused for new_x output)
  const float* xy    = (const float*)d_in[4];
  const float* W     = (const float*)d_in[5];
  const float* bias  = (const float*)d_in[6];
  const float* a_src = (const float*)d_in[7];
  const float* a_dst = (const float*)d_in[8];
  const float* t_src = (const float*)d_in[9];
  const float* t_dst = (const float*)d_in[10];
  const float* p     = (const float*)d_in[11];
  const float* gamma = (const float*)d_in[12];
  const float* beta  = (const float*)d_in[13];

  int N = in_sizes[0] / D;
  int E = in_sizes[1] / 2;
  const int* srcA = ei;
  const int* dstA = ei + E;

  char* ws = (char*)d_ws;
  size_t off = 0;
  auto alloc = [&](size_t bytes) -> void* {
    void* r = ws + off;
    off += (bytes + 255) & ~(size_t)255;
    return r;
  };
  float*    h0     = (float*)alloc((size_t)N*D*4);   // reused as h2 later
  float*    h1     = (float*)alloc((size_t)N*D*4);
  float*    hs     = (float*)alloc((size_t)N*4);
  float*    hd     = (float*)alloc((size_t)N*4);
  float*    ht     = (float*)alloc((size_t)N*4);
  float*    pn     = (float*)alloc(4);
  float*    wbuf   = (float*)alloc((size_t)E*4);     // logit then exp-weight
  int*      seg    = (int*)alloc((size_t)E*4);
  unsigned* segmax = (unsigned*)alloc((size_t)N*NT*4);
  float*    segsum = (float*)alloc((size_t)N*NT*4);
  int*      cnt    = (int*)alloc((size_t)N*NT*4);
  int*      offs   = (int*)alloc((size_t)N*NT*4);
  int*      cursor = (int*)alloc((size_t)N*NT*4);
  int*      sorted = (int*)alloc((size_t)E*4);
  float*    scoreA = (float*)alloc((size_t)N*4);
  int*      centers= (int*)alloc(KC*4);
  float*    cpos   = (float*)alloc(KC*2*4);
  float*    xsum   = (float*)alloc((size_t)KC*D*4);
  float*    denom  = (float*)alloc(KC*4);

  hipMemsetAsync(segmax, 0, (size_t)N*NT*4, stream);
  hipMemsetAsync(segsum, 0, (size_t)N*NT*4, stream);
  hipMemsetAsync(cnt,    0, (size_t)N*NT*4, stream);
  hipMemsetAsync(cursor, 0, (size_t)N*NT*4, stream);
  hipMemsetAsync(xsum,   0, (size_t)KC*D*4, stream);
  hipMemsetAsync(denom,  0, (size_t)KC*4, stream);

  ln_kernel<<<N, 256, 0, stream>>>(x, gamma, beta, h0, N);

  dim3 ggrid((N + 63)/64, D/64);
  gemm_bias<<<ggrid, 256, 0, stream>>>(h0, W, bias, h1, N);

  rowdots<<<N, 256, 0, stream>>>(h1, a_src, a_dst, t_dst, hs, hd, ht, N);
  pnorm_kernel<<<1, 256, 0, stream>>>(p, pn);

  int eb = (E + 255)/256;
  edge_logit<<<eb, 256, 0, stream>>>(srcA, dstA, ntype, hd, hs, wbuf, seg, segmax, cnt, E);
  edge_exp<<<eb, 256, 0, stream>>>(wbuf, seg, segmax, segsum, E);
  scan_excl<<<1, 1024, 0, stream>>>(cnt, offs, N*NT);
  scatter_k<<<eb, 256, 0, stream>>>(seg, offs, cursor, sorted, E);

  float* h2 = h0;  // overlay: h0 no longer needed after GEMM
  node_combine<<<N, 256, 0, stream>>>(h1, wbuf, sorted, offs, cnt, segsum, srcA,
                                      ht, t_src, gamma, beta, p, pn, h2, scoreA, N);

  topk_kernel<<<1, 1024, 0, stream>>>(scoreA, xy, centers, cpos, N);
  pool_kernel<<<128, 256, 0, stream>>>(h2, scoreA, xy, cpos, xsum, denom, N);
  fin_kernel<<<KC, 256, 0, stream>>>(xsum, denom, (float*)d_out);
}

// Round 6
// 746.526 us; speedup vs baseline: 1.6628x; 1.6628x over previous
//
#include <hip/hip_runtime.h>
#include <math.h>

#define D 512
#define NT 3
#define KC 10
#define MAXE 128
#define TKB 64

typedef __attribute__((ext_vector_type(8))) short bf16x8;
typedef __attribute__((ext_vector_type(4))) float f32x4;

// ---------- helpers ----------

__device__ __forceinline__ unsigned encf(float f){
  unsigned u = __float_as_uint(f);
  return (u & 0x80000000u) ? ~u : (u | 0x80000000u);
}
__device__ __forceinline__ float decf(unsigned u){
  return (u & 0x80000000u) ? __uint_as_float(u & 0x7fffffffu)
                           : __uint_as_float(~u);
}
__device__ __forceinline__ float leaky(float x){ return x > 0.f ? x : 0.2f * x; }

__device__ __forceinline__ unsigned short f2bf(float f){
  unsigned u = __float_as_uint(f);
  u += 0x7fff + ((u >> 16) & 1);
  return (unsigned short)(u >> 16);
}
__device__ __forceinline__ float bf2f(unsigned short h){
  return __uint_as_float(((unsigned)h) << 16);
}

__device__ __forceinline__ void gload_lds16(const void* g, void* l){
  __builtin_amdgcn_global_load_lds((const __attribute__((address_space(1))) void*)g,
                                   (__attribute__((address_space(3))) void*)l, 16, 0, 0);
}

// block reduce for 256-thread blocks (4 waves of 64)
__device__ __forceinline__ float4 bsum4(float4 v, float* lds){
  for (int o = 32; o > 0; o >>= 1){
    v.x += __shfl_down(v.x, o);
    v.y += __shfl_down(v.y, o);
    v.z += __shfl_down(v.z, o);
    v.w += __shfl_down(v.w, o);
  }
  int w = threadIdx.x >> 6, l = threadIdx.x & 63;
  if (l == 0){ lds[w*4+0]=v.x; lds[w*4+1]=v.y; lds[w*4+2]=v.z; lds[w*4+3]=v.w; }
  __syncthreads();
  float4 r;
  r.x = lds[0]+lds[4]+lds[8]+lds[12];
  r.y = lds[1]+lds[5]+lds[9]+lds[13];
  r.z = lds[2]+lds[6]+lds[10]+lds[14];
  r.w = lds[3]+lds[7]+lds[11]+lds[15];
  __syncthreads();
  return r;
}

__device__ __forceinline__ int wave_incl_scan(int v){
  int lane = threadIdx.x & 63;
  for (int o = 1; o < 64; o <<= 1){
    int t = __shfl_up(v, o);
    if (lane >= o) v += t;
  }
  return v;
}

// ---------- kernels ----------

// LayerNorm -> bf16 hi/lo split (row-major)
__launch_bounds__(256) __global__
void ln_kernel(const float* __restrict__ x, const float* __restrict__ g,
               const float* __restrict__ b, unsigned short* __restrict__ Ahi,
               unsigned short* __restrict__ Alo, int N){
  __shared__ float lds[16];
  int n = blockIdx.x, tid = threadIdx.x;
  float v0 = x[(size_t)n*D + tid], v1 = x[(size_t)n*D + tid + 256];
  float4 s = bsum4(make_float4(v0+v1, v0*v0+v1*v1, 0.f, 0.f), lds);
  float mu = s.x * (1.f/D);
  float var = s.y * (1.f/D) - mu*mu;
  float r = rsqrtf(var + 1e-5f);
  float g0 = (v0-mu)*r*g[tid]     + b[tid];
  float g1 = (v1-mu)*r*g[tid+256] + b[tid+256];
  unsigned short h0 = f2bf(g0), h1v = f2bf(g1);
  Ahi[(size_t)n*D + tid]       = h0;
  Alo[(size_t)n*D + tid]       = f2bf(g0 - bf2f(h0));
  Ahi[(size_t)n*D + tid + 256] = h1v;
  Alo[(size_t)n*D + tid + 256] = f2bf(g1 - bf2f(h1v));
}

// W -> transposed K-chunk packed bf16 hi/lo: Wp[n][kbg] chunk = {W[kbg*8..+8][n]}
__launch_bounds__(256) __global__
void wprep(const float* __restrict__ W, unsigned short* __restrict__ Bh,
           unsigned short* __restrict__ Bl){
  __shared__ float wt[8][512];
  int kbg = blockIdx.x, tid = threadIdx.x;
  for (int i = tid; i < 8*512; i += 256){
    int k = i >> 9, n = i & 511;
    wt[k][n] = W[(size_t)(kbg*8 + k)*512 + n];
  }
  __syncthreads();
  for (int n = tid; n < 512; n += 256){
    bf16x8 hv, lv;
    #pragma unroll
    for (int j = 0; j < 8; ++j){
      float v = wt[j][n];
      unsigned short hh = f2bf(v);
      hv[j] = (short)hh;
      lv[j] = (short)f2bf(v - bf2f(hh));
    }
    size_t cb = ((size_t)n*64 + kbg)*8;
    *(bf16x8*)(Bh + cb) = hv;
    *(bf16x8*)(Bl + cb) = lv;
  }
}

// MFMA GEMM: C[M,512] = A @ W + bias, A=hi+lo bf16, 3-term product.
// 128x128 tile, BK=32, 4 waves (2x2), 4x4 16x16x32 frags/wave.
__launch_bounds__(256) __global__
void gemm_mfma(const unsigned short* __restrict__ Ahi, const unsigned short* __restrict__ Alo,
               const unsigned short* __restrict__ Bph, const unsigned short* __restrict__ Bpl,
               const float* __restrict__ bias, float* __restrict__ C, int M){
  __shared__ unsigned short Ah[128*32], Al[128*32], Bh[128*32], Bl[128*32]; // 4 x 8KB
  int tid = threadIdx.x;
  int row0 = blockIdx.x * 128, col0 = blockIdx.y * 128;
  int w = tid >> 6, lane = tid & 63;
  int wr = w >> 1, wc = w & 1;
  int lr = lane & 15, lg = lane >> 4;
  f32x4 acc[4][4];
  #pragma unroll
  for (int i = 0; i < 4; ++i)
    #pragma unroll
    for (int j = 0; j < 4; ++j)
      acc[i][j] = (f32x4){0.f, 0.f, 0.f, 0.f};

  const size_t arow = (size_t)row0 * D;
  for (int k0 = 0; k0 < D; k0 += 32){
    int k0b = k0 >> 3;
    #pragma unroll
    for (int q = 0; q < 2; ++q){
      int c = q*256 + tid;
      int m = c >> 2, slot = c & 3;
      int kb = slot ^ ((m >> 1) & 3);
      size_t ga = arow + (size_t)m*D + k0 + kb*8;       // element idx (ushort)
      gload_lds16(Ahi + ga, Ah + (size_t)c*8);
      gload_lds16(Alo + ga, Al + (size_t)c*8);
      size_t gb = ((size_t)(col0 + m)*64 + k0b + kb)*8; // chunk idx *8 shorts
      gload_lds16(Bph + gb, Bh + (size_t)c*8);
      gload_lds16(Bpl + gb, Bl + (size_t)c*8);
    }
    __syncthreads();
    bf16x8 afh[4], afl[4], bfh[4], bfl[4];
    #pragma unroll
    for (int f = 0; f < 4; ++f){
      int m = wr*64 + f*16 + lr;
      int sA = lg ^ ((m >> 1) & 3);
      afh[f] = *(const bf16x8*)(Ah + (size_t)(m*4 + sA)*8);
      afl[f] = *(const bf16x8*)(Al + (size_t)(m*4 + sA)*8);
      int nn = wc*64 + f*16 + lr;
      int sB = lg ^ ((nn >> 1) & 3);
      bfh[f] = *(const bf16x8*)(Bh + (size_t)(nn*4 + sB)*8);
      bfl[f] = *(const bf16x8*)(Bl + (size_t)(nn*4 + sB)*8);
    }
    #pragma unroll
    for (int i = 0; i < 4; ++i)
      #pragma unroll
      for (int j = 0; j < 4; ++j){
        acc[i][j] = __builtin_amdgcn_mfma_f32_16x16x32_bf16(afh[i], bfh[j], acc[i][j], 0, 0, 0);
        acc[i][j] = __builtin_amdgcn_mfma_f32_16x16x32_bf16(afh[i], bfl[j], acc[i][j], 0, 0, 0);
        acc[i][j] = __builtin_amdgcn_mfma_f32_16x16x32_bf16(afl[i], bfh[j], acc[i][j], 0, 0, 0);
      }
    __syncthreads();
  }
  #pragma unroll
  for (int j = 0; j < 4; ++j){
    int col = col0 + wc*64 + j*16 + lr;
    float bv = bias[col];
    #pragma unroll
    for (int i = 0; i < 4; ++i){
      int rbase = row0 + wr*64 + i*16 + lg*4;
      #pragma unroll
      for (int r = 0; r < 4; ++r){
        int rr = rbase + r;
        if (rr < M) C[(size_t)rr*D + col] = acc[i][j][r] + bv;
      }
    }
  }
}

// per-row dots of h1 with a_src, a_dst, t_dst
__launch_bounds__(256) __global__
void rowdots(const float* __restrict__ h1, const float* __restrict__ a_src,
             const float* __restrict__ a_dst, const float* __restrict__ t_dst,
             float* __restrict__ hs, float* __restrict__ hd, float* __restrict__ ht,
             int N){
  __shared__ float lds[16];
  int n = blockIdx.x, tid = threadIdx.x;
  float v0 = h1[(size_t)n*D + tid], v1 = h1[(size_t)n*D + tid + 256];
  float4 s = bsum4(make_float4(v0*a_src[tid] + v1*a_src[tid+256],
                               v0*a_dst[tid] + v1*a_dst[tid+256],
                               v0*t_dst[tid] + v1*t_dst[tid+256], 0.f), lds);
  if (tid == 0){ hs[n] = s.x; hd[n] = s.y; ht[n] = s.z; }
}

__launch_bounds__(256) __global__
void pnorm_kernel(const float* __restrict__ p, float* __restrict__ pn){
  __shared__ float lds[16];
  int tid = threadIdx.x;
  float v0 = p[tid], v1 = p[tid+256];
  float4 s = bsum4(make_float4(v0*v0 + v1*v1, 0.f, 0.f, 0.f), lds);
  if (tid == 0) pn[0] = sqrtf(s.x);
}

__launch_bounds__(256) __global__
void edge_logit(const int* __restrict__ src, const int* __restrict__ dst,
                const int* __restrict__ ntype,
                const float* __restrict__ hd, const float* __restrict__ hs,
                float* __restrict__ logit, int* __restrict__ seg,
                unsigned* __restrict__ segmax, int* __restrict__ cnt, int E){
  int e = blockIdx.x*256 + threadIdx.x;
  if (e >= E) return;
  int s = src[e], d = dst[e];
  float l = leaky(hd[d] + hs[s]);
  int sg = d*NT + ntype[s];
  logit[e] = l;
  seg[e] = sg;
  atomicMax(&segmax[sg], encf(l));
  atomicAdd(&cnt[sg], 1);
}

__launch_bounds__(256) __global__
void edge_exp(float* __restrict__ logit_w, const int* __restrict__ seg,
              const unsigned* __restrict__ segmax, float* __restrict__ segsum, int E){
  int e = blockIdx.x*256 + threadIdx.x;
  if (e >= E) return;
  int sg = seg[e];
  float w = expf(logit_w[e] - decf(segmax[sg]));
  logit_w[e] = w;
  atomicAdd(&segsum[sg], w);
}

// hierarchical exclusive scan: part sums -> top scan -> final
__launch_bounds__(256) __global__
void scan_part(const int* __restrict__ cnt, int* __restrict__ bsum, int n){
  int b = blockIdx.x, tid = threadIdx.x;
  int i = b*1024 + tid*4;
  int4 v = make_int4(0,0,0,0);
  if (i + 3 < n) v = *(const int4*)(cnt + i);
  else {
    if (i   < n) v.x = cnt[i];
    if (i+1 < n) v.y = cnt[i+1];
    if (i+2 < n) v.z = cnt[i+2];
    if (i+3 < n) v.w = cnt[i+3];
  }
  int s = v.x+v.y+v.z+v.w;
  int sc = wave_incl_scan(s);
  __shared__ int wsum[4];
  if ((tid & 63) == 63) wsum[tid>>6] = sc;
  __syncthreads();
  if (tid == 0) bsum[b] = wsum[0]+wsum[1]+wsum[2]+wsum[3];
}

__launch_bounds__(128) __global__
void scan_top(int* __restrict__ bsum, int nb){
  int tid = threadIdx.x;
  int v = (tid < nb) ? bsum[tid] : 0;
  int sc = wave_incl_scan(v);
  __shared__ int w0;
  if (tid == 63) w0 = sc;
  __syncthreads();
  if (tid >= 64) sc += w0;
  if (tid < nb) bsum[tid] = sc - v;
}

__launch_bounds__(256) __global__
void scan_final(const int* __restrict__ cnt, const int* __restrict__ boffs,
                int* __restrict__ offs, int n){
  int b = blockIdx.x, tid = threadIdx.x;
  int i = b*1024 + tid*4;
  int4 v = make_int4(0,0,0,0);
  if (i + 3 < n) v = *(const int4*)(cnt + i);
  else {
    if (i   < n) v.x = cnt[i];
    if (i+1 < n) v.y = cnt[i+1];
    if (i+2 < n) v.z = cnt[i+2];
    if (i+3 < n) v.w = cnt[i+3];
  }
  int s = v.x+v.y+v.z+v.w;
  int sc = wave_incl_scan(s);
  __shared__ int wsum[4];
  if ((tid & 63) == 63) wsum[tid>>6] = sc;
  __syncthreads();
  int w = tid >> 6;
  int wbase = 0;
  for (int j = 0; j < w; ++j) wbase += wsum[j];
  int excl = boffs[b] + wbase + sc - s;
  if (i   < n) offs[i]   = excl;
  if (i+1 < n) offs[i+1] = excl + v.x;
  if (i+2 < n) offs[i+2] = excl + v.x + v.y;
  if (i+3 < n) offs[i+3] = excl + v.x + v.y + v.z;
}

__launch_bounds__(256) __global__
void scatter_k(const int* __restrict__ seg, const int* __restrict__ offs,
               int* __restrict__ cursor, int* __restrict__ sorted, int E){
  int e = blockIdx.x*256 + threadIdx.x;
  if (e >= E) return;
  int sg = seg[e];
  int p = atomicAdd(&cursor[sg], 1);
  sorted[offs[sg] + p] = e;
}

// per node: LDS-prefetched edges, unroll-2 aggregation, beta softmax, LN, score
__launch_bounds__(256) __global__
void node_combine(const float* __restrict__ h1, const float* __restrict__ wbuf,
                  const int* __restrict__ sorted, const int* __restrict__ offs,
                  const int* __restrict__ cnt, const float* __restrict__ segsum,
                  const int* __restrict__ srcA,
                  const float* __restrict__ ht, const float* __restrict__ t_src,
                  const float* __restrict__ gamma, const float* __restrict__ beta,
                  const float* __restrict__ p, const float* __restrict__ pn,
                  float* __restrict__ h2, float* __restrict__ score, int N){
  __shared__ float lds[16];
  __shared__ float wa[MAXE];
  __shared__ int   wsrc[MAXE];
  __shared__ float sinv[NT];
  int n = blockIdx.x, tid = threadIdx.x;
  int i0 = tid, i1 = tid + 256;
  int base = offs[n*NT];
  int c0 = cnt[n*NT], c1 = cnt[n*NT+1], c2 = cnt[n*NT+2];
  int total = c0 + c1 + c2;
  for (int k = tid; k < total && k < MAXE; k += 256){
    int e = sorted[base + k];
    wa[k] = wbuf[e];
    wsrc[k] = srcA[e];
  }
  if (tid < NT) sinv[tid] = 1.f / (segsum[n*NT + tid] + 1e-16f);
  __syncthreads();

  float acc[NT][2] = {};
  int bounds[4] = {0, c0, c0 + c1, total};
  #pragma unroll
  for (int t = 0; t < NT; ++t){
    int lo = bounds[t], hiB = bounds[t+1];
    float a0, a1; int s0, s1;
    int k = lo;
    for (; k + 2 <= hiB; k += 2){
      if (k + 1 < MAXE){ a0 = wa[k]; s0 = wsrc[k]; a1 = wa[k+1]; s1 = wsrc[k+1]; }
      else {
        if (k < MAXE){ a0 = wa[k]; s0 = wsrc[k]; }
        else { int e0 = sorted[base+k]; a0 = wbuf[e0]; s0 = srcA[e0]; }
        int e1 = sorted[base+k+1]; a1 = wbuf[e1]; s1 = srcA[e1];
      }
      const float* r0 = h1 + (size_t)s0*D;
      const float* r1 = h1 + (size_t)s1*D;
      float p00 = r0[i0], p01 = r0[i1];
      float p10 = r1[i0], p11 = r1[i1];
      acc[t][0] += a0*p00;
      acc[t][1] += a0*p01;
      acc[t][0] += a1*p10;
      acc[t][1] += a1*p11;
    }
    if (k < hiB){
      float a; int s;
      if (k < MAXE){ a = wa[k]; s = wsrc[k]; }
      else { int e = sorted[base+k]; a = wbuf[e]; s = srcA[e]; }
      const float* r0 = h1 + (size_t)s*D;
      acc[t][0] += a*r0[i0];
      acc[t][1] += a*r0[i1];
    }
    acc[t][0] *= sinv[t];
    acc[t][1] *= sinv[t];
  }

  float ts0 = t_src[i0], ts1 = t_src[i1];
  float4 dt = bsum4(make_float4(acc[0][0]*ts0 + acc[0][1]*ts1,
                                acc[1][0]*ts0 + acc[1][1]*ts1,
                                acc[2][0]*ts0 + acc[2][1]*ts1, 0.f), lds);
  float htn = ht[n];
  float bl0 = c0 > 0 ? leaky(htn + dt.x) : -1e9f;
  float bl1 = c1 > 0 ? leaky(htn + dt.y) : -1e9f;
  float bl2 = c2 > 0 ? leaky(htn + dt.z) : -1e9f;
  float mx = fmaxf(bl0, fmaxf(bl1, bl2));
  float e0 = expf(bl0 - mx), e1 = expf(bl1 - mx), e2 = expf(bl2 - mx);
  float invs = 1.f / (e0 + e1 + e2);
  float o0 = (e0*acc[0][0] + e1*acc[1][0] + e2*acc[2][0]) * invs;
  float o1 = (e0*acc[0][1] + e1*acc[1][1] + e2*acc[2][1]) * invs;
  float4 s2 = bsum4(make_float4(o0 + o1, o0*o0 + o1*o1, 0.f, 0.f), lds);
  float mu = s2.x * (1.f/D);
  float var = s2.y * (1.f/D) - mu*mu;
  float r = rsqrtf(var + 1e-5f);
  float g0 = (o0 - mu)*r*gamma[i0] + beta[i0];
  float g1 = (o1 - mu)*r*gamma[i1] + beta[i1];
  h2[(size_t)n*D + i0] = g0;
  h2[(size_t)n*D + i1] = g1;
  float4 s3 = bsum4(make_float4(g0*p[i0] + g1*p[i1], 0.f, 0.f, 0.f), lds);
  if (tid == 0){
    float z = s3.x / (pn[0] + 1e-6f);
    score[n] = 1.f / (1.f + expf(-z));
  }
}

// two-stage exact top-10 (order: score desc, index asc — matches jax.lax.top_k)
__launch_bounds__(256) __global__
void topk_local(const float* __restrict__ score, float* __restrict__ cv,
                int* __restrict__ ci, int N){
  int b = blockIdx.x, tid = threadIdx.x;
  int step = (N + TKB - 1) / TKB;
  int lo = b * step;
  int hi = min(N, lo + step);
  __shared__ float wv[4]; __shared__ int wi[4];
  __shared__ int chosen[KC];
  for (int it = 0; it < KC; ++it){
    float bv = -INFINITY; int bi = 0x7fffffff;
    for (int i = lo + tid; i < hi; i += 256){
      bool skip = false;
      for (int t = 0; t < it; ++t) if (chosen[t] == i) skip = true;
      if (skip) continue;
      float v = score[i];
      if (v > bv || (v == bv && i < bi)){ bv = v; bi = i; }
    }
    for (int o = 32; o > 0; o >>= 1){
      float ov = __shfl_down(bv, o); int oi = __shfl_down(bi, o);
      if (ov > bv || (ov == bv && oi < bi)){ bv = ov; bi = oi; }
    }
    if ((tid & 63) == 0){ wv[tid>>6] = bv; wi[tid>>6] = bi; }
    __syncthreads();
    if (tid == 0){
      for (int w2 = 1; w2 < 4; ++w2)
        if (wv[w2] > wv[0] || (wv[w2] == wv[0] && wi[w2] < wi[0])){ wv[0]=wv[w2]; wi[0]=wi[w2]; }
      chosen[it] = wi[0];
      cv[b*KC + it] = wv[0]; ci[b*KC + it] = wi[0];
    }
    __syncthreads();
  }
}

__launch_bounds__(256) __global__
void topk_merge(const float* __restrict__ cv, const int* __restrict__ ci,
                const float* __restrict__ xy, int* __restrict__ centers,
                float* __restrict__ cpos){
  const int NC = TKB * KC;
  __shared__ float sv[TKB*KC]; __shared__ int si[TKB*KC];
  __shared__ float wv[4]; __shared__ int wi[4]; __shared__ int wp[4];
  __shared__ int chosenpos[KC];
  int tid = threadIdx.x;
  for (int i = tid; i < NC; i += 256){ sv[i] = cv[i]; si[i] = ci[i]; }
  __syncthreads();
  for (int it = 0; it < KC; ++it){
    float bv = -INFINITY; int bi = 0x7fffffff; int bp = -1;
    for (int i = tid; i < NC; i += 256){
      bool skip = false;
      for (int t = 0; t < it; ++t) if (chosenpos[t] == i) skip = true;
      if (skip) continue;
      float v = sv[i];
      if (v > bv || (v == bv && si[i] < bi)){ bv = v; bi = si[i]; bp = i; }
    }
    for (int o = 32; o > 0; o >>= 1){
      float ov = __shfl_down(bv, o); int oi = __shfl_down(bi, o); int op = __shfl_down(bp, o);
      if (ov > bv || (ov == bv && oi < bi)){ bv = ov; bi = oi; bp = op; }
    }
    if ((tid & 63) == 0){ wv[tid>>6] = bv; wi[tid>>6] = bi; wp[tid>>6] = bp; }
    __syncthreads();
    if (tid == 0){
      int bw = 0;
      for (int w2 = 1; w2 < 4; ++w2)
        if (wv[w2] > wv[bw] || (wv[w2] == wv[bw] && wi[w2] < wi[bw])) bw = w2;
      chosenpos[it] = wp[bw];
      centers[it] = wi[bw];
      cpos[it*2+0] = xy[(size_t)wi[bw]*2+0]*2.f - 1.f;
      cpos[it*2+1] = xy[(size_t)wi[bw]*2+1]*2.f - 1.f;
    }
    __syncthreads();
  }
}

__launch_bounds__(256) __global__
void pool_kernel(const float* __restrict__ h2, const float* __restrict__ score,
                 const float* __restrict__ xy, const float* __restrict__ cpos,
                 float* __restrict__ xsum, float* __restrict__ denom, int N){
  __shared__ float accs[KC][D];
  __shared__ float dsum[KC];
  __shared__ float cp[KC*2];
  int tid = threadIdx.x;
  for (int i = tid; i < KC*D; i += 256) ((float*)accs)[i] = 0.f;
  if (tid < KC) dsum[tid] = 0.f;
  if (tid < KC*2) cp[tid] = cpos[tid];
  __syncthreads();
  for (int n = blockIdx.x; n < N; n += gridDim.x){
    float px = xy[(size_t)n*2+0]*2.f - 1.f;
    float py = xy[(size_t)n*2+1]*2.f - 1.f;
    int best = 0; float bd = 3.4e38f;
    #pragma unroll
    for (int k = 0; k < KC; ++k){
      float dx = px - cp[k*2], dy = py - cp[k*2+1];
      float d2v = dx*dx + dy*dy;
      if (d2v < bd){ bd = d2v; best = k; }
    }
    float s = score[n];
    accs[best][tid]       += s * h2[(size_t)n*D + tid];
    accs[best][tid + 256] += s * h2[(size_t)n*D + tid + 256];
    if (tid == 0) dsum[best] += s;
  }
  __syncthreads();
  for (int i = tid; i < KC*D; i += 256) atomicAdd(&xsum[i], ((float*)accs)[i]);
  if (tid < KC) atomicAdd(&denom[tid], dsum[tid]);
}

__launch_bounds__(256) __global__
void fin_kernel(const float* __restrict__ xsum, const float* __restrict__ denom,
                float* __restrict__ out){
  int k = blockIdx.x, tid = threadIdx.x;
  float inv = 1.f / (denom[k] + 1e-6f);
  out[(size_t)k*D + tid]       = xsum[(size_t)k*D + tid] * inv;
  out[(size_t)k*D + tid + 256] = xsum[(size_t)k*D + tid + 256] * inv;
}

// ---------- launch ----------

extern "C" void kernel_launch(void* const* d_in, const int* in_sizes, int n_in,
                              void* d_out, int out_size, void* d_ws, size_t ws_size,
                              hipStream_t stream){
  const float* x     = (const float*)d_in[0];
  const int*   ei    = (const int*)d_in[1];
  const int*   ntype = (const int*)d_in[2];
  const float* xy    = (const float*)d_in[4];
  const float* W     = (const float*)d_in[5];
  const float* bias  = (const float*)d_in[6];
  const float* a_src = (const float*)d_in[7];
  const float* a_dst = (const float*)d_in[8];
  const float* t_src = (const float*)d_in[9];
  const float* t_dst = (const float*)d_in[10];
  const float* p     = (const float*)d_in[11];
  const float* gamma = (const float*)d_in[12];
  const float* beta  = (const float*)d_in[13];

  int N = in_sizes[0] / D;
  int E = in_sizes[1] / 2;
  const int* srcA = ei;
  const int* dstA = ei + E;
  int Mpad = ((N + 127) / 128) * 128;

  char* ws = (char*)d_ws;
  size_t off = 0;
  auto alloc = [&](size_t bytes) -> void* {
    void* r = ws + off;
    off += (bytes + 255) & ~(size_t)255;
    return r;
  };
  unsigned short* Ahi = (unsigned short*)alloc((size_t)Mpad*D*2);  // h2 overlays later
  unsigned short* Alo = (unsigned short*)alloc((size_t)Mpad*D*2);
  float*    h1     = (float*)alloc((size_t)N*D*4);
  unsigned short* Wph = (unsigned short*)alloc((size_t)D*D*2);
  unsigned short* Wpl = (unsigned short*)alloc((size_t)D*D*2);
  float*    hs     = (float*)alloc((size_t)N*4);
  float*    hd     = (float*)alloc((size_t)N*4);
  float*    ht     = (float*)alloc((size_t)N*4);
  float*    pn     = (float*)alloc(4);
  float*    wbuf   = (float*)alloc((size_t)E*4);
  int*      seg    = (int*)alloc((size_t)E*4);
  unsigned* segmax = (unsigned*)alloc((size_t)N*NT*4);
  float*    segsum = (float*)alloc((size_t)N*NT*4);
  int*      cnt    = (int*)alloc((size_t)N*NT*4);
  int*      offs   = (int*)alloc((size_t)N*NT*4);
  int*      cursor = (int*)alloc((size_t)N*NT*4);
  int*      bsum   = (int*)alloc(128*4);
  int*      sorted = (int*)alloc((size_t)E*4);
  float*    scoreA = (float*)alloc((size_t)N*4);
  float*    cv     = (float*)alloc(TKB*KC*4);
  int*      ci     = (int*)alloc(TKB*KC*4);
  int*      centers= (int*)alloc(KC*4);
  float*    cpos   = (float*)alloc(KC*2*4);
  float*    xsum   = (float*)alloc((size_t)KC*D*4);
  float*    denom  = (float*)alloc(KC*4);

  hipMemsetAsync(segmax, 0, (size_t)N*NT*4, stream);
  hipMemsetAsync(segsum, 0, (size_t)N*NT*4, stream);
  hipMemsetAsync(cnt,    0, (size_t)N*NT*4, stream);
  hipMemsetAsync(cursor, 0, (size_t)N*NT*4, stream);
  hipMemsetAsync(xsum,   0, (size_t)KC*D*4, stream);
  hipMemsetAsync(denom,  0, (size_t)KC*4, stream);

  ln_kernel<<<N, 256, 0, stream>>>(x, gamma, beta, Ahi, Alo, N);
  wprep<<<64, 256, 0, stream>>>(W, Wph, Wpl);

  dim3 ggrid(Mpad/128, 4);
  gemm_mfma<<<ggrid, 256, 0, stream>>>(Ahi, Alo, Wph, Wpl, bias, h1, N);

  rowdots<<<N, 256, 0, stream>>>(h1, a_src, a_dst, t_dst, hs, hd, ht, N);
  pnorm_kernel<<<1, 256, 0, stream>>>(p, pn);

  int eb = (E + 255)/256;
  edge_logit<<<eb, 256, 0, stream>>>(srcA, dstA, ntype, hd, hs, wbuf, seg, segmax, cnt, E);
  edge_exp<<<eb, 256, 0, stream>>>(wbuf, seg, segmax, segsum, E);

  int nseg = N*NT;
  int nb = (nseg + 1023)/1024;
  scan_part<<<nb, 256, 0, stream>>>(cnt, bsum, nseg);
  scan_top<<<1, 128, 0, stream>>>(bsum, nb);
  scan_final<<<nb, 256, 0, stream>>>(cnt, bsum, offs, nseg);
  scatter_k<<<eb, 256, 0, stream>>>(seg, offs, cursor, sorted, E);

  float* h2 = (float*)Ahi;  // overlay: Ahi/Alo dead after gemm
  node_combine<<<N, 256, 0, stream>>>(h1, wbuf, sorted, offs, cnt, segsum, srcA,
                                      ht, t_src, gamma, beta, p, pn, h2, scoreA, N);

  topk_local<<<TKB, 256, 0, stream>>>(scoreA, cv, ci, N);
  topk_merge<<<1, 256, 0, stream>>>(cv, ci, xy, centers, cpos);
  pool_kernel<<<128, 256, 0, stream>>>(h2, scoreA, xy, cpos, xsum, denom, N);
  fin_kernel<<<KC, 256, 0, stream>>>(xsum, denom, (float*)d_out);
}

// Round 7
// 613.174 us; speedup vs baseline: 2.0244x; 1.2175x over previous
//
#include <hip/hip_runtime.h>
#include <math.h>

#define D 512
#define NT 3
#define KC 10
#define MAXE 128
#define TKB 64

typedef __attribute__((ext_vector_type(8))) short bf16x8;
typedef __attribute__((ext_vector_type(4))) float f32x4;

// ---------- helpers ----------

__device__ __forceinline__ unsigned encf(float f){
  unsigned u = __float_as_uint(f);
  return (u & 0x80000000u) ? ~u : (u | 0x80000000u);
}
__device__ __forceinline__ float decf(unsigned u){
  return (u & 0x80000000u) ? __uint_as_float(u & 0x7fffffffu)
                           : __uint_as_float(~u);
}
__device__ __forceinline__ float leaky(float x){ return x > 0.f ? x : 0.2f * x; }

__device__ __forceinline__ unsigned short f2bf(float f){
  unsigned u = __float_as_uint(f);
  u += 0x7fff + ((u >> 16) & 1);
  return (unsigned short)(u >> 16);
}
__device__ __forceinline__ float bf2f(unsigned short h){
  return __uint_as_float(((unsigned)h) << 16);
}

__device__ __forceinline__ void gload_lds16(const void* g, void* l){
  __builtin_amdgcn_global_load_lds((const __attribute__((address_space(1))) void*)g,
                                   (__attribute__((address_space(3))) void*)l, 16, 0, 0);
}

// block reduce for 256-thread blocks (4 waves of 64)
__device__ __forceinline__ float4 bsum4(float4 v, float* lds){
  for (int o = 32; o > 0; o >>= 1){
    v.x += __shfl_down(v.x, o);
    v.y += __shfl_down(v.y, o);
    v.z += __shfl_down(v.z, o);
    v.w += __shfl_down(v.w, o);
  }
  int w = threadIdx.x >> 6, l = threadIdx.x & 63;
  if (l == 0){ lds[w*4+0]=v.x; lds[w*4+1]=v.y; lds[w*4+2]=v.z; lds[w*4+3]=v.w; }
  __syncthreads();
  float4 r;
  r.x = lds[0]+lds[4]+lds[8]+lds[12];
  r.y = lds[1]+lds[5]+lds[9]+lds[13];
  r.z = lds[2]+lds[6]+lds[10]+lds[14];
  r.w = lds[3]+lds[7]+lds[11]+lds[15];
  __syncthreads();
  return r;
}

__device__ __forceinline__ int wave_incl_scan(int v){
  int lane = threadIdx.x & 63;
  for (int o = 1; o < 64; o <<= 1){
    int t = __shfl_up(v, o);
    if (lane >= o) v += t;
  }
  return v;
}

// ---------- kernels ----------

// LayerNorm -> bf16 hi/lo split (row-major)
__launch_bounds__(256) __global__
void ln_kernel(const float* __restrict__ x, const float* __restrict__ g,
               const float* __restrict__ b, unsigned short* __restrict__ Ahi,
               unsigned short* __restrict__ Alo, int N){
  __shared__ float lds[16];
  int n = blockIdx.x, tid = threadIdx.x;
  float v0 = x[(size_t)n*D + tid], v1 = x[(size_t)n*D + tid + 256];
  float4 s = bsum4(make_float4(v0+v1, v0*v0+v1*v1, 0.f, 0.f), lds);
  float mu = s.x * (1.f/D);
  float var = s.y * (1.f/D) - mu*mu;
  float r = rsqrtf(var + 1e-5f);
  float g0 = (v0-mu)*r*g[tid]     + b[tid];
  float g1 = (v1-mu)*r*g[tid+256] + b[tid+256];
  unsigned short h0 = f2bf(g0), h1v = f2bf(g1);
  Ahi[(size_t)n*D + tid]       = h0;
  Alo[(size_t)n*D + tid]       = f2bf(g0 - bf2f(h0));
  Ahi[(size_t)n*D + tid + 256] = h1v;
  Alo[(size_t)n*D + tid + 256] = f2bf(g1 - bf2f(h1v));
}

// W -> transposed K-chunk packed bf16 hi/lo: Wp[n][kbg] chunk = {W[kbg*8..+8][n]}
__launch_bounds__(256) __global__
void wprep(const float* __restrict__ W, unsigned short* __restrict__ Bh,
           unsigned short* __restrict__ Bl){
  __shared__ float wt[8][512];
  int kbg = blockIdx.x, tid = threadIdx.x;
  for (int i = tid; i < 8*512; i += 256){
    int k = i >> 9, n = i & 511;
    wt[k][n] = W[(size_t)(kbg*8 + k)*512 + n];
  }
  __syncthreads();
  for (int n = tid; n < 512; n += 256){
    bf16x8 hv, lv;
    #pragma unroll
    for (int j = 0; j < 8; ++j){
      float v = wt[j][n];
      unsigned short hh = f2bf(v);
      hv[j] = (short)hh;
      lv[j] = (short)f2bf(v - bf2f(hh));
    }
    size_t cb = ((size_t)n*64 + kbg)*8;
    *(bf16x8*)(Bh + cb) = hv;
    *(bf16x8*)(Bl + cb) = lv;
  }
}

// MFMA GEMM: C[M,512] = A @ W + bias, A=hi+lo bf16, 3-term product.
// 128x128 tile, BK=32, 4 waves (2x2), 4x4 16x16x32 frags/wave.
__launch_bounds__(256) __global__
void gemm_mfma(const unsigned short* __restrict__ Ahi, const unsigned short* __restrict__ Alo,
               const unsigned short* __restrict__ Bph, const unsigned short* __restrict__ Bpl,
               const float* __restrict__ bias, float* __restrict__ C, int M){
  __shared__ unsigned short Ah[128*32], Al[128*32], Bh[128*32], Bl[128*32]; // 4 x 8KB
  int tid = threadIdx.x;
  int row0 = blockIdx.x * 128, col0 = blockIdx.y * 128;
  int w = tid >> 6, lane = tid & 63;
  int wr = w >> 1, wc = w & 1;
  int lr = lane & 15, lg = lane >> 4;
  f32x4 acc[4][4];
  #pragma unroll
  for (int i = 0; i < 4; ++i)
    #pragma unroll
    for (int j = 0; j < 4; ++j)
      acc[i][j] = (f32x4){0.f, 0.f, 0.f, 0.f};

  const size_t arow = (size_t)row0 * D;
  for (int k0 = 0; k0 < D; k0 += 32){
    int k0b = k0 >> 3;
    #pragma unroll
    for (int q = 0; q < 2; ++q){
      int c = q*256 + tid;
      int m = c >> 2, slot = c & 3;
      int kb = slot ^ ((m >> 1) & 3);
      size_t ga = arow + (size_t)m*D + k0 + kb*8;       // element idx (ushort)
      gload_lds16(Ahi + ga, Ah + (size_t)c*8);
      gload_lds16(Alo + ga, Al + (size_t)c*8);
      size_t gb = ((size_t)(col0 + m)*64 + k0b + kb)*8; // chunk idx *8 shorts
      gload_lds16(Bph + gb, Bh + (size_t)c*8);
      gload_lds16(Bpl + gb, Bl + (size_t)c*8);
    }
    __syncthreads();
    bf16x8 afh[4], afl[4], bfh[4], bfl[4];
    #pragma unroll
    for (int f = 0; f < 4; ++f){
      int m = wr*64 + f*16 + lr;
      int sA = lg ^ ((m >> 1) & 3);
      afh[f] = *(const bf16x8*)(Ah + (size_t)(m*4 + sA)*8);
      afl[f] = *(const bf16x8*)(Al + (size_t)(m*4 + sA)*8);
      int nn = wc*64 + f*16 + lr;
      int sB = lg ^ ((nn >> 1) & 3);
      bfh[f] = *(const bf16x8*)(Bh + (size_t)(nn*4 + sB)*8);
      bfl[f] = *(const bf16x8*)(Bl + (size_t)(nn*4 + sB)*8);
    }
    #pragma unroll
    for (int i = 0; i < 4; ++i)
      #pragma unroll
      for (int j = 0; j < 4; ++j){
        acc[i][j] = __builtin_amdgcn_mfma_f32_16x16x32_bf16(afh[i], bfh[j], acc[i][j], 0, 0, 0);
        acc[i][j] = __builtin_amdgcn_mfma_f32_16x16x32_bf16(afh[i], bfl[j], acc[i][j], 0, 0, 0);
        acc[i][j] = __builtin_amdgcn_mfma_f32_16x16x32_bf16(afl[i], bfh[j], acc[i][j], 0, 0, 0);
      }
    __syncthreads();
  }
  #pragma unroll
  for (int j = 0; j < 4; ++j){
    int col = col0 + wc*64 + j*16 + lr;
    float bv = bias[col];
    #pragma unroll
    for (int i = 0; i < 4; ++i){
      int rbase = row0 + wr*64 + i*16 + lg*4;
      #pragma unroll
      for (int r = 0; r < 4; ++r){
        int rr = rbase + r;
        if (rr < M) C[(size_t)rr*D + col] = acc[i][j][r] + bv;
      }
    }
  }
}

// per-row dots of h1 with a_src, a_dst, t_dst
__launch_bounds__(256) __global__
void rowdots(const float* __restrict__ h1, const float* __restrict__ a_src,
             const float* __restrict__ a_dst, const float* __restrict__ t_dst,
             float* __restrict__ hs, float* __restrict__ hd, float* __restrict__ ht,
             int N){
  __shared__ float lds[16];
  int n = blockIdx.x, tid = threadIdx.x;
  float v0 = h1[(size_t)n*D + tid], v1 = h1[(size_t)n*D + tid + 256];
  float4 s = bsum4(make_float4(v0*a_src[tid] + v1*a_src[tid+256],
                               v0*a_dst[tid] + v1*a_dst[tid+256],
                               v0*t_dst[tid] + v1*t_dst[tid+256], 0.f), lds);
  if (tid == 0){ hs[n] = s.x; hd[n] = s.y; ht[n] = s.z; }
}

__launch_bounds__(256) __global__
void pnorm_kernel(const float* __restrict__ p, float* __restrict__ pn){
  __shared__ float lds[16];
  int tid = threadIdx.x;
  float v0 = p[tid], v1 = p[tid+256];
  float4 s = bsum4(make_float4(v0*v0 + v1*v1, 0.f, 0.f, 0.f), lds);
  if (tid == 0) pn[0] = sqrtf(s.x);
}

__launch_bounds__(256) __global__
void edge_logit(const int* __restrict__ src, const int* __restrict__ dst,
                const int* __restrict__ ntype,
                const float* __restrict__ hd, const float* __restrict__ hs,
                float* __restrict__ logit, int* __restrict__ seg,
                unsigned* __restrict__ segmax, int* __restrict__ cnt, int E){
  int e = blockIdx.x*256 + threadIdx.x;
  if (e >= E) return;
  int s = src[e], d = dst[e];
  float l = leaky(hd[d] + hs[s]);
  int sg = d*NT + ntype[s];
  logit[e] = l;
  seg[e] = sg;
  atomicMax(&segmax[sg], encf(l));
  atomicAdd(&cnt[sg], 1);
}

__launch_bounds__(256) __global__
void edge_exp(float* __restrict__ logit_w, const int* __restrict__ seg,
              const unsigned* __restrict__ segmax, float* __restrict__ segsum, int E){
  int e = blockIdx.x*256 + threadIdx.x;
  if (e >= E) return;
  int sg = seg[e];
  float w = expf(logit_w[e] - decf(segmax[sg]));
  logit_w[e] = w;
  atomicAdd(&segsum[sg], w);
}

// hierarchical exclusive scan: part sums -> top scan -> final
__launch_bounds__(256) __global__
void scan_part(const int* __restrict__ cnt, int* __restrict__ bsum, int n){
  int b = blockIdx.x, tid = threadIdx.x;
  int i = b*1024 + tid*4;
  int4 v = make_int4(0,0,0,0);
  if (i + 3 < n) v = *(const int4*)(cnt + i);
  else {
    if (i   < n) v.x = cnt[i];
    if (i+1 < n) v.y = cnt[i+1];
    if (i+2 < n) v.z = cnt[i+2];
    if (i+3 < n) v.w = cnt[i+3];
  }
  int s = v.x+v.y+v.z+v.w;
  int sc = wave_incl_scan(s);
  __shared__ int wsum[4];
  if ((tid & 63) == 63) wsum[tid>>6] = sc;
  __syncthreads();
  if (tid == 0) bsum[b] = wsum[0]+wsum[1]+wsum[2]+wsum[3];
}

__launch_bounds__(128) __global__
void scan_top(int* __restrict__ bsum, int nb){
  int tid = threadIdx.x;
  int v = (tid < nb) ? bsum[tid] : 0;
  int sc = wave_incl_scan(v);
  __shared__ int w0;
  if (tid == 63) w0 = sc;
  __syncthreads();
  if (tid >= 64) sc += w0;
  if (tid < nb) bsum[tid] = sc - v;
}

__launch_bounds__(256) __global__
void scan_final(const int* __restrict__ cnt, const int* __restrict__ boffs,
                int* __restrict__ offs, int n){
  int b = blockIdx.x, tid = threadIdx.x;
  int i = b*1024 + tid*4;
  int4 v = make_int4(0,0,0,0);
  if (i + 3 < n) v = *(const int4*)(cnt + i);
  else {
    if (i   < n) v.x = cnt[i];
    if (i+1 < n) v.y = cnt[i+1];
    if (i+2 < n) v.z = cnt[i+2];
    if (i+3 < n) v.w = cnt[i+3];
  }
  int s = v.x+v.y+v.z+v.w;
  int sc = wave_incl_scan(s);
  __shared__ int wsum[4];
  if ((tid & 63) == 63) wsum[tid>>6] = sc;
  __syncthreads();
  int w = tid >> 6;
  int wbase = 0;
  for (int j = 0; j < w; ++j) wbase += wsum[j];
  int excl = boffs[b] + wbase + sc - s;
  if (i   < n) offs[i]   = excl;
  if (i+1 < n) offs[i+1] = excl + v.x;
  if (i+2 < n) offs[i+2] = excl + v.x + v.y;
  if (i+3 < n) offs[i+3] = excl + v.x + v.y + v.z;
}

__launch_bounds__(256) __global__
void scatter_k(const int* __restrict__ seg, const int* __restrict__ offs,
               int* __restrict__ cursor, int* __restrict__ sorted, int E){
  int e = blockIdx.x*256 + threadIdx.x;
  if (e >= E) return;
  int sg = seg[e];
  int p = atomicAdd(&cursor[sg], 1);
  sorted[offs[sg] + p] = e;
}

// per node: LDS-prefetched edges, unroll-2 aggregation, beta softmax, LN, score
__launch_bounds__(256) __global__
void node_combine(const float* __restrict__ h1, const float* __restrict__ wbuf,
                  const int* __restrict__ sorted, const int* __restrict__ offs,
                  const int* __restrict__ cnt, const float* __restrict__ segsum,
                  const int* __restrict__ srcA,
                  const float* __restrict__ ht, const float* __restrict__ t_src,
                  const float* __restrict__ gamma, const float* __restrict__ beta,
                  const float* __restrict__ p, const float* __restrict__ pn,
                  float* __restrict__ h2, float* __restrict__ score, int N){
  __shared__ float lds[16];
  __shared__ float wa[MAXE];
  __shared__ int   wsrc[MAXE];
  __shared__ float sinv[NT];
  int n = blockIdx.x, tid = threadIdx.x;
  int i0 = tid, i1 = tid + 256;
  int base = offs[n*NT];
  int c0 = cnt[n*NT], c1 = cnt[n*NT+1], c2 = cnt[n*NT+2];
  int total = c0 + c1 + c2;
  for (int k = tid; k < total && k < MAXE; k += 256){
    int e = sorted[base + k];
    wa[k] = wbuf[e];
    wsrc[k] = srcA[e];
  }
  if (tid < NT) sinv[tid] = 1.f / (segsum[n*NT + tid] + 1e-16f);
  __syncthreads();

  float acc[NT][2] = {};
  int bounds[4] = {0, c0, c0 + c1, total};
  #pragma unroll
  for (int t = 0; t < NT; ++t){
    int lo = bounds[t], hiB = bounds[t+1];
    float a0, a1; int s0, s1;
    int k = lo;
    for (; k + 2 <= hiB; k += 2){
      if (k + 1 < MAXE){ a0 = wa[k]; s0 = wsrc[k]; a1 = wa[k+1]; s1 = wsrc[k+1]; }
      else {
        if (k < MAXE){ a0 = wa[k]; s0 = wsrc[k]; }
        else { int e0 = sorted[base+k]; a0 = wbuf[e0]; s0 = srcA[e0]; }
        int e1 = sorted[base+k+1]; a1 = wbuf[e1]; s1 = srcA[e1];
      }
      const float* r0 = h1 + (size_t)s0*D;
      const float* r1 = h1 + (size_t)s1*D;
      float p00 = r0[i0], p01 = r0[i1];
      float p10 = r1[i0], p11 = r1[i1];
      acc[t][0] += a0*p00;
      acc[t][1] += a0*p01;
      acc[t][0] += a1*p10;
      acc[t][1] += a1*p11;
    }
    if (k < hiB){
      float a; int s;
      if (k < MAXE){ a = wa[k]; s = wsrc[k]; }
      else { int e = sorted[base+k]; a = wbuf[e]; s = srcA[e]; }
      const float* r0 = h1 + (size_t)s*D;
      acc[t][0] += a*r0[i0];
      acc[t][1] += a*r0[i1];
    }
    acc[t][0] *= sinv[t];
    acc[t][1] *= sinv[t];
  }

  float ts0 = t_src[i0], ts1 = t_src[i1];
  float4 dt = bsum4(make_float4(acc[0][0]*ts0 + acc[0][1]*ts1,
                                acc[1][0]*ts0 + acc[1][1]*ts1,
                                acc[2][0]*ts0 + acc[2][1]*ts1, 0.f), lds);
  float htn = ht[n];
  float bl0 = c0 > 0 ? leaky(htn + dt.x) : -1e9f;
  float bl1 = c1 > 0 ? leaky(htn + dt.y) : -1e9f;
  float bl2 = c2 > 0 ? leaky(htn + dt.z) : -1e9f;
  float mx = fmaxf(bl0, fmaxf(bl1, bl2));
  float e0 = expf(bl0 - mx), e1 = expf(bl1 - mx), e2 = expf(bl2 - mx);
  float invs = 1.f / (e0 + e1 + e2);
  float o0 = (e0*acc[0][0] + e1*acc[1][0] + e2*acc[2][0]) * invs;
  float o1 = (e0*acc[0][1] + e1*acc[1][1] + e2*acc[2][1]) * invs;
  float4 s2 = bsum4(make_float4(o0 + o1, o0*o0 + o1*o1, 0.f, 0.f), lds);
  float mu = s2.x * (1.f/D);
  float var = s2.y * (1.f/D) - mu*mu;
  float r = rsqrtf(var + 1e-5f);
  float g0 = (o0 - mu)*r*gamma[i0] + beta[i0];
  float g1 = (o1 - mu)*r*gamma[i1] + beta[i1];
  h2[(size_t)n*D + i0] = g0;
  h2[(size_t)n*D + i1] = g1;
  float4 s3 = bsum4(make_float4(g0*p[i0] + g1*p[i1], 0.f, 0.f, 0.f), lds);
  if (tid == 0){
    float z = s3.x / (pn[0] + 1e-6f);
    score[n] = 1.f / (1.f + expf(-z));
  }
}

// two-stage exact top-10 (order: score desc, index asc — matches jax.lax.top_k)
__launch_bounds__(256) __global__
void topk_local(const float* __restrict__ score, float* __restrict__ cv,
                int* __restrict__ ci, int N){
  int b = blockIdx.x, tid = threadIdx.x;
  int step = (N + TKB - 1) / TKB;
  int lo = b * step;
  int hi = min(N, lo + step);
  __shared__ float wv[4]; __shared__ int wi[4];
  __shared__ int chosen[KC];
  for (int it = 0; it < KC; ++it){
    float bv = -INFINITY; int bi = 0x7fffffff;
    for (int i = lo + tid; i < hi; i += 256){
      bool skip = false;
      for (int t = 0; t < it; ++t) if (chosen[t] == i) skip = true;
      if (skip) continue;
      float v = score[i];
      if (v > bv || (v == bv && i < bi)){ bv = v; bi = i; }
    }
    for (int o = 32; o > 0; o >>= 1){
      float ov = __shfl_down(bv, o); int oi = __shfl_down(bi, o);
      if (ov > bv || (ov == bv && oi < bi)){ bv = ov; bi = oi; }
    }
    if ((tid & 63) == 0){ wv[tid>>6] = bv; wi[tid>>6] = bi; }
    __syncthreads();
    if (tid == 0){
      for (int w2 = 1; w2 < 4; ++w2)
        if (wv[w2] > wv[0] || (wv[w2] == wv[0] && wi[w2] < wi[0])){ wv[0]=wv[w2]; wi[0]=wi[w2]; }
      chosen[it] = wi[0];
      cv[b*KC + it] = wv[0]; ci[b*KC + it] = wi[0];
    }
    __syncthreads();
  }
}

__launch_bounds__(256) __global__
void topk_merge(const float* __restrict__ cv, const int* __restrict__ ci,
                const float* __restrict__ xy, int* __restrict__ centers,
                float* __restrict__ cpos){
  const int NC = TKB * KC;
  __shared__ float sv[TKB*KC]; __shared__ int si[TKB*KC];
  __shared__ float wv[4]; __shared__ int wi[4]; __shared__ int wp[4];
  __shared__ int chosenpos[KC];
  int tid = threadIdx.x;
  for (int i = tid; i < NC; i += 256){ sv[i] = cv[i]; si[i] = ci[i]; }
  __syncthreads();
  for (int it = 0; it < KC; ++it){
    float bv = -INFINITY; int bi = 0x7fffffff; int bp = -1;
    for (int i = tid; i < NC; i += 256){
      bool skip = false;
      for (int t = 0; t < it; ++t) if (chosenpos[t] == i) skip = true;
      if (skip) continue;
      float v = sv[i];
      if (v > bv || (v == bv && si[i] < bi)){ bv = v; bi = si[i]; bp = i; }
    }
    for (int o = 32; o > 0; o >>= 1){
      float ov = __shfl_down(bv, o); int oi = __shfl_down(bi, o); int op = __shfl_down(bp, o);
      if (ov > bv || (ov == bv && oi < bi)){ bv = ov; bi = oi; bp = op; }
    }
    if ((tid & 63) == 0){ wv[tid>>6] = bv; wi[tid>>6] = bi; wp[tid>>6] = bp; }
    __syncthreads();
    if (tid == 0){
      int bw = 0;
      for (int w2 = 1; w2 < 4; ++w2)
        if (wv[w2] > wv[bw] || (wv[w2] == wv[bw] && wi[w2] < wi[bw])) bw = w2;
      chosenpos[it] = wp[bw];
      centers[it] = wi[bw];
      cpos[it*2+0] = xy[(size_t)wi[bw]*2+0]*2.f - 1.f;
      cpos[it*2+1] = xy[(size_t)wi[bw]*2+1]*2.f - 1.f;
    }
    __syncthreads();
  }
}

// register-accumulator pooling: no LDS RMW chain, 512 blocks, unroll-2.
// Each thread owns columns (tid, tid+256) of all KC cluster accumulators
// (compile-time k indexing -> registers, rule #20); denom: thread k owns cluster k.
__launch_bounds__(256) __global__
void pool_kernel(const float* __restrict__ h2, const float* __restrict__ score,
                 const float* __restrict__ xy, const float* __restrict__ cpos,
                 float* __restrict__ xsum, float* __restrict__ denom, int N){
  int tid = threadIdx.x;
  float cpx[KC], cpy[KC];
  #pragma unroll
  for (int k = 0; k < KC; ++k){ cpx[k] = cpos[2*k]; cpy[k] = cpos[2*k+1]; }
  float acc0[KC], acc1[KC];
  #pragma unroll
  for (int k = 0; k < KC; ++k){ acc0[k] = 0.f; acc1[k] = 0.f; }
  float ds = 0.f;
  int stride = gridDim.x;
  for (int n = blockIdx.x; n < N; n += 2*stride){
    int n2 = n + stride;
    // node A
    float px = xy[2*(size_t)n]*2.f - 1.f, py = xy[2*(size_t)n+1]*2.f - 1.f;
    float sA = score[n];
    float vA0 = h2[(size_t)n*D + tid], vA1 = h2[(size_t)n*D + tid + 256];
    // node B (independent loads in flight with A's compute)
    float qx = 0.f, qy = 0.f, sB = 0.f, vB0 = 0.f, vB1 = 0.f;
    bool hasB = n2 < N;
    if (hasB){
      qx = xy[2*(size_t)n2]*2.f - 1.f; qy = xy[2*(size_t)n2+1]*2.f - 1.f;
      sB = score[n2];
      vB0 = h2[(size_t)n2*D + tid]; vB1 = h2[(size_t)n2*D + tid + 256];
    }
    int bestA = 0, bestB = 0;
    float bdA = 3.4e38f, bdB = 3.4e38f;
    #pragma unroll
    for (int k = 0; k < KC; ++k){
      float dax = px - cpx[k], day = py - cpy[k];
      float dA = dax*dax + day*day;
      if (dA < bdA){ bdA = dA; bestA = k; }
      float dbx = qx - cpx[k], dby = qy - cpy[k];
      float dB = dbx*dbx + dby*dby;
      if (dB < bdB){ bdB = dB; bestB = k; }
    }
    float wA0 = sA*vA0, wA1 = sA*vA1;
    float wB0 = hasB ? sB*vB0 : 0.f, wB1 = hasB ? sB*vB1 : 0.f;
    #pragma unroll
    for (int k = 0; k < KC; ++k){
      acc0[k] += (bestA == k) ? wA0 : 0.f;
      acc1[k] += (bestA == k) ? wA1 : 0.f;
      acc0[k] += (hasB && bestB == k) ? wB0 : 0.f;
      acc1[k] += (hasB && bestB == k) ? wB1 : 0.f;
    }
    ds += (bestA == tid) ? sA : 0.f;
    ds += (hasB && bestB == tid) ? sB : 0.f;
  }
  #pragma unroll
  for (int k = 0; k < KC; ++k){
    atomicAdd(&xsum[(size_t)k*D + tid],       acc0[k]);
    atomicAdd(&xsum[(size_t)k*D + tid + 256], acc1[k]);
  }
  if (tid < KC) atomicAdd(&denom[tid], ds);
}

__launch_bounds__(256) __global__
void fin_kernel(const float* __restrict__ xsum, const float* __restrict__ denom,
                float* __restrict__ out){
  int k = blockIdx.x, tid = threadIdx.x;
  float inv = 1.f / (denom[k] + 1e-6f);
  out[(size_t)k*D + tid]       = xsum[(size_t)k*D + tid] * inv;
  out[(size_t)k*D + tid + 256] = xsum[(size_t)k*D + tid + 256] * inv;
}

// ---------- launch ----------

extern "C" void kernel_launch(void* const* d_in, const int* in_sizes, int n_in,
                              void* d_out, int out_size, void* d_ws, size_t ws_size,
                              hipStream_t stream){
  const float* x     = (const float*)d_in[0];
  const int*   ei    = (const int*)d_in[1];
  const int*   ntype = (const int*)d_in[2];
  const float* xy    = (const float*)d_in[4];
  const float* W     = (const float*)d_in[5];
  const float* bias  = (const float*)d_in[6];
  const float* a_src = (const float*)d_in[7];
  const float* a_dst = (const float*)d_in[8];
  const float* t_src = (const float*)d_in[9];
  const float* t_dst = (const float*)d_in[10];
  const float* p     = (const float*)d_in[11];
  const float* gamma = (const float*)d_in[12];
  const float* beta  = (const float*)d_in[13];

  int N = in_sizes[0] / D;
  int E = in_sizes[1] / 2;
  const int* srcA = ei;
  const int* dstA = ei + E;
  int Mpad = ((N + 127) / 128) * 128;

  char* ws = (char*)d_ws;
  size_t off = 0;
  auto alloc = [&](size_t bytes) -> void* {
    void* r = ws + off;
    off += (bytes + 255) & ~(size_t)255;
    return r;
  };
  unsigned short* Ahi = (unsigned short*)alloc((size_t)Mpad*D*2);  // h2 overlays later
  unsigned short* Alo = (unsigned short*)alloc((size_t)Mpad*D*2);
  float*    h1     = (float*)alloc((size_t)N*D*4);
  unsigned short* Wph = (unsigned short*)alloc((size_t)D*D*2);
  unsigned short* Wpl = (unsigned short*)alloc((size_t)D*D*2);
  float*    hs     = (float*)alloc((size_t)N*4);
  float*    hd     = (float*)alloc((size_t)N*4);
  float*    ht     = (float*)alloc((size_t)N*4);
  float*    pn     = (float*)alloc(4);
  float*    wbuf   = (float*)alloc((size_t)E*4);
  int*      seg    = (int*)alloc((size_t)E*4);
  unsigned* segmax = (unsigned*)alloc((size_t)N*NT*4);
  float*    segsum = (float*)alloc((size_t)N*NT*4);
  int*      cnt    = (int*)alloc((size_t)N*NT*4);
  int*      offs   = (int*)alloc((size_t)N*NT*4);
  int*      cursor = (int*)alloc((size_t)N*NT*4);
  int*      bsum   = (int*)alloc(128*4);
  int*      sorted = (int*)alloc((size_t)E*4);
  float*    scoreA = (float*)alloc((size_t)N*4);
  float*    cv     = (float*)alloc(TKB*KC*4);
  int*      ci     = (int*)alloc(TKB*KC*4);
  int*      centers= (int*)alloc(KC*4);
  float*    cpos   = (float*)alloc(KC*2*4);
  float*    xsum   = (float*)alloc((size_t)KC*D*4);
  float*    denom  = (float*)alloc(KC*4);

  hipMemsetAsync(segmax, 0, (size_t)N*NT*4, stream);
  hipMemsetAsync(segsum, 0, (size_t)N*NT*4, stream);
  hipMemsetAsync(cnt,    0, (size_t)N*NT*4, stream);
  hipMemsetAsync(cursor, 0, (size_t)N*NT*4, stream);
  hipMemsetAsync(xsum,   0, (size_t)KC*D*4, stream);
  hipMemsetAsync(denom,  0, (size_t)KC*4, stream);

  ln_kernel<<<N, 256, 0, stream>>>(x, gamma, beta, Ahi, Alo, N);
  wprep<<<64, 256, 0, stream>>>(W, Wph, Wpl);

  dim3 ggrid(Mpad/128, 4);
  gemm_mfma<<<ggrid, 256, 0, stream>>>(Ahi, Alo, Wph, Wpl, bias, h1, N);

  rowdots<<<N, 256, 0, stream>>>(h1, a_src, a_dst, t_dst, hs, hd, ht, N);
  pnorm_kernel<<<1, 256, 0, stream>>>(p, pn);

  int eb = (E + 255)/256;
  edge_logit<<<eb, 256, 0, stream>>>(srcA, dstA, ntype, hd, hs, wbuf, seg, segmax, cnt, E);
  edge_exp<<<eb, 256, 0, stream>>>(wbuf, seg, segmax, segsum, E);

  int nseg = N*NT;
  int nb = (nseg + 1023)/1024;
  scan_part<<<nb, 256, 0, stream>>>(cnt, bsum, nseg);
  scan_top<<<1, 128, 0, stream>>>(bsum, nb);
  scan_final<<<nb, 256, 0, stream>>>(cnt, bsum, offs, nseg);
  scatter_k<<<eb, 256, 0, stream>>>(seg, offs, cursor, sorted, E);

  float* h2 = (float*)Ahi;  // overlay: Ahi/Alo dead after gemm
  node_combine<<<N, 256, 0, stream>>>(h1, wbuf, sorted, offs, cnt, segsum, srcA,
                                      ht, t_src, gamma, beta, p, pn, h2, scoreA, N);

  topk_local<<<TKB, 256, 0, stream>>>(scoreA, cv, ci, N);
  topk_merge<<<1, 256, 0, stream>>>(cv, ci, xy, centers, cpos);
  pool_kernel<<<512, 256, 0, stream>>>(h2, scoreA, xy, cpos, xsum, denom, N);
  fin_kernel<<<KC, 256, 0, stream>>>(xsum, denom, (float*)d_out);
}

// Round 8
// 609.331 us; speedup vs baseline: 2.0371x; 1.0063x over previous
//
#include <hip/hip_runtime.h>
#include <math.h>

#define D 512
#define NT 3
#define KC 10
#define MAXE 128
#define TKB 64

typedef __attribute__((ext_vector_type(8))) short bf16x8;
typedef __attribute__((ext_vector_type(4))) float f32x4;

// ---------- helpers ----------

__device__ __forceinline__ unsigned encf(float f){
  unsigned u = __float_as_uint(f);
  return (u & 0x80000000u) ? ~u : (u | 0x80000000u);
}
__device__ __forceinline__ float decf(unsigned u){
  return (u & 0x80000000u) ? __uint_as_float(u & 0x7fffffffu)
                           : __uint_as_float(~u);
}
__device__ __forceinline__ float leaky(float x){ return x > 0.f ? x : 0.2f * x; }

__device__ __forceinline__ unsigned short f2bf(float f){
  unsigned u = __float_as_uint(f);
  u += 0x7fff + ((u >> 16) & 1);
  return (unsigned short)(u >> 16);
}
__device__ __forceinline__ float bf2f(unsigned short h){
  return __uint_as_float(((unsigned)h) << 16);
}

__device__ __forceinline__ void gload_lds16(const void* g, void* l){
  __builtin_amdgcn_global_load_lds((const __attribute__((address_space(1))) void*)g,
                                   (__attribute__((address_space(3))) void*)l, 16, 0, 0);
}

// block reduce for 256-thread blocks (4 waves of 64)
__device__ __forceinline__ float4 bsum4(float4 v, float* lds){
  for (int o = 32; o > 0; o >>= 1){
    v.x += __shfl_down(v.x, o);
    v.y += __shfl_down(v.y, o);
    v.z += __shfl_down(v.z, o);
    v.w += __shfl_down(v.w, o);
  }
  int w = threadIdx.x >> 6, l = threadIdx.x & 63;
  if (l == 0){ lds[w*4+0]=v.x; lds[w*4+1]=v.y; lds[w*4+2]=v.z; lds[w*4+3]=v.w; }
  __syncthreads();
  float4 r;
  r.x = lds[0]+lds[4]+lds[8]+lds[12];
  r.y = lds[1]+lds[5]+lds[9]+lds[13];
  r.z = lds[2]+lds[6]+lds[10]+lds[14];
  r.w = lds[3]+lds[7]+lds[11]+lds[15];
  __syncthreads();
  return r;
}

// block reduce for 128-thread blocks (2 waves of 64)
__device__ __forceinline__ float4 bsum4_128(float4 v, float* lds){
  for (int o = 32; o > 0; o >>= 1){
    v.x += __shfl_down(v.x, o);
    v.y += __shfl_down(v.y, o);
    v.z += __shfl_down(v.z, o);
    v.w += __shfl_down(v.w, o);
  }
  int w = threadIdx.x >> 6, l = threadIdx.x & 63;
  if (l == 0){ lds[w*4+0]=v.x; lds[w*4+1]=v.y; lds[w*4+2]=v.z; lds[w*4+3]=v.w; }
  __syncthreads();
  float4 r;
  r.x = lds[0]+lds[4];
  r.y = lds[1]+lds[5];
  r.z = lds[2]+lds[6];
  r.w = lds[3]+lds[7];
  __syncthreads();
  return r;
}

__device__ __forceinline__ int wave_incl_scan(int v){
  int lane = threadIdx.x & 63;
  for (int o = 1; o < 64; o <<= 1){
    int t = __shfl_up(v, o);
    if (lane >= o) v += t;
  }
  return v;
}

// ---------- kernels ----------

// LayerNorm -> bf16 hi/lo split (row-major)
__launch_bounds__(256) __global__
void ln_kernel(const float* __restrict__ x, const float* __restrict__ g,
               const float* __restrict__ b, unsigned short* __restrict__ Ahi,
               unsigned short* __restrict__ Alo, int N){
  __shared__ float lds[16];
  int n = blockIdx.x, tid = threadIdx.x;
  float v0 = x[(size_t)n*D + tid], v1 = x[(size_t)n*D + tid + 256];
  float4 s = bsum4(make_float4(v0+v1, v0*v0+v1*v1, 0.f, 0.f), lds);
  float mu = s.x * (1.f/D);
  float var = s.y * (1.f/D) - mu*mu;
  float r = rsqrtf(var + 1e-5f);
  float g0 = (v0-mu)*r*g[tid]     + b[tid];
  float g1 = (v1-mu)*r*g[tid+256] + b[tid+256];
  unsigned short h0 = f2bf(g0), h1v = f2bf(g1);
  Ahi[(size_t)n*D + tid]       = h0;
  Alo[(size_t)n*D + tid]       = f2bf(g0 - bf2f(h0));
  Ahi[(size_t)n*D + tid + 256] = h1v;
  Alo[(size_t)n*D + tid + 256] = f2bf(g1 - bf2f(h1v));
}

// W -> transposed K-chunk packed bf16 hi/lo: Wp[n][kbg] chunk = {W[kbg*8..+8][n]}
__launch_bounds__(256) __global__
void wprep(const float* __restrict__ W, unsigned short* __restrict__ Bh,
           unsigned short* __restrict__ Bl){
  __shared__ float wt[8][512];
  int kbg = blockIdx.x, tid = threadIdx.x;
  for (int i = tid; i < 8*512; i += 256){
    int k = i >> 9, n = i & 511;
    wt[k][n] = W[(size_t)(kbg*8 + k)*512 + n];
  }
  __syncthreads();
  for (int n = tid; n < 512; n += 256){
    bf16x8 hv, lv;
    #pragma unroll
    for (int j = 0; j < 8; ++j){
      float v = wt[j][n];
      unsigned short hh = f2bf(v);
      hv[j] = (short)hh;
      lv[j] = (short)f2bf(v - bf2f(hh));
    }
    size_t cb = ((size_t)n*64 + kbg)*8;
    *(bf16x8*)(Bh + cb) = hv;
    *(bf16x8*)(Bl + cb) = lv;
  }
}

// MFMA GEMM: C[M,512] = A @ W + bias, A=hi+lo bf16, 3-term product.
// 128x128 tile, BK=32, 4 waves (2x2), 4x4 16x16x32 frags/wave.
__launch_bounds__(256) __global__
void gemm_mfma(const unsigned short* __restrict__ Ahi, const unsigned short* __restrict__ Alo,
               const unsigned short* __restrict__ Bph, const unsigned short* __restrict__ Bpl,
               const float* __restrict__ bias, float* __restrict__ C, int M){
  __shared__ unsigned short Ah[128*32], Al[128*32], Bh[128*32], Bl[128*32]; // 4 x 8KB
  int tid = threadIdx.x;
  int row0 = blockIdx.x * 128, col0 = blockIdx.y * 128;
  int w = tid >> 6, lane = tid & 63;
  int wr = w >> 1, wc = w & 1;
  int lr = lane & 15, lg = lane >> 4;
  f32x4 acc[4][4];
  #pragma unroll
  for (int i = 0; i < 4; ++i)
    #pragma unroll
    for (int j = 0; j < 4; ++j)
      acc[i][j] = (f32x4){0.f, 0.f, 0.f, 0.f};

  const size_t arow = (size_t)row0 * D;
  for (int k0 = 0; k0 < D; k0 += 32){
    int k0b = k0 >> 3;
    #pragma unroll
    for (int q = 0; q < 2; ++q){
      int c = q*256 + tid;
      int m = c >> 2, slot = c & 3;
      int kb = slot ^ ((m >> 1) & 3);
      size_t ga = arow + (size_t)m*D + k0 + kb*8;       // element idx (ushort)
      gload_lds16(Ahi + ga, Ah + (size_t)c*8);
      gload_lds16(Alo + ga, Al + (size_t)c*8);
      size_t gb = ((size_t)(col0 + m)*64 + k0b + kb)*8; // chunk idx *8 shorts
      gload_lds16(Bph + gb, Bh + (size_t)c*8);
      gload_lds16(Bpl + gb, Bl + (size_t)c*8);
    }
    __syncthreads();
    bf16x8 afh[4], afl[4], bfh[4], bfl[4];
    #pragma unroll
    for (int f = 0; f < 4; ++f){
      int m = wr*64 + f*16 + lr;
      int sA = lg ^ ((m >> 1) & 3);
      afh[f] = *(const bf16x8*)(Ah + (size_t)(m*4 + sA)*8);
      afl[f] = *(const bf16x8*)(Al + (size_t)(m*4 + sA)*8);
      int nn = wc*64 + f*16 + lr;
      int sB = lg ^ ((nn >> 1) & 3);
      bfh[f] = *(const bf16x8*)(Bh + (size_t)(nn*4 + sB)*8);
      bfl[f] = *(const bf16x8*)(Bl + (size_t)(nn*4 + sB)*8);
    }
    #pragma unroll
    for (int i = 0; i < 4; ++i)
      #pragma unroll
      for (int j = 0; j < 4; ++j){
        acc[i][j] = __builtin_amdgcn_mfma_f32_16x16x32_bf16(afh[i], bfh[j], acc[i][j], 0, 0, 0);
        acc[i][j] = __builtin_amdgcn_mfma_f32_16x16x32_bf16(afh[i], bfl[j], acc[i][j], 0, 0, 0);
        acc[i][j] = __builtin_amdgcn_mfma_f32_16x16x32_bf16(afl[i], bfh[j], acc[i][j], 0, 0, 0);
      }
    __syncthreads();
  }
  #pragma unroll
  for (int j = 0; j < 4; ++j){
    int col = col0 + wc*64 + j*16 + lr;
    float bv = bias[col];
    #pragma unroll
    for (int i = 0; i < 4; ++i){
      int rbase = row0 + wr*64 + i*16 + lg*4;
      #pragma unroll
      for (int r = 0; r < 4; ++r){
        int rr = rbase + r;
        if (rr < M) C[(size_t)rr*D + col] = acc[i][j][r] + bv;
      }
    }
  }
}

// per-row dots of h1 with a_src, a_dst, t_dst
__launch_bounds__(256) __global__
void rowdots(const float* __restrict__ h1, const float* __restrict__ a_src,
             const float* __restrict__ a_dst, const float* __restrict__ t_dst,
             float* __restrict__ hs, float* __restrict__ hd, float* __restrict__ ht,
             int N){
  __shared__ float lds[16];
  int n = blockIdx.x, tid = threadIdx.x;
  float v0 = h1[(size_t)n*D + tid], v1 = h1[(size_t)n*D + tid + 256];
  float4 s = bsum4(make_float4(v0*a_src[tid] + v1*a_src[tid+256],
                               v0*a_dst[tid] + v1*a_dst[tid+256],
                               v0*t_dst[tid] + v1*t_dst[tid+256], 0.f), lds);
  if (tid == 0){ hs[n] = s.x; hd[n] = s.y; ht[n] = s.z; }
}

__launch_bounds__(256) __global__
void pnorm_kernel(const float* __restrict__ p, float* __restrict__ pn){
  __shared__ float lds[16];
  int tid = threadIdx.x;
  float v0 = p[tid], v1 = p[tid+256];
  float4 s = bsum4(make_float4(v0*v0 + v1*v1, 0.f, 0.f, 0.f), lds);
  if (tid == 0) pn[0] = sqrtf(s.x);
}

__launch_bounds__(256) __global__
void edge_logit(const int* __restrict__ src, const int* __restrict__ dst,
                const int* __restrict__ ntype,
                const float* __restrict__ hd, const float* __restrict__ hs,
                float* __restrict__ logit, int* __restrict__ seg,
                unsigned* __restrict__ segmax, int* __restrict__ cnt, int E){
  int e = blockIdx.x*256 + threadIdx.x;
  if (e >= E) return;
  int s = src[e], d = dst[e];
  float l = leaky(hd[d] + hs[s]);
  int sg = d*NT + ntype[s];
  logit[e] = l;
  seg[e] = sg;
  atomicMax(&segmax[sg], encf(l));
  atomicAdd(&cnt[sg], 1);
}

__launch_bounds__(256) __global__
void edge_exp(float* __restrict__ logit_w, const int* __restrict__ seg,
              const unsigned* __restrict__ segmax, float* __restrict__ segsum, int E){
  int e = blockIdx.x*256 + threadIdx.x;
  if (e >= E) return;
  int sg = seg[e];
  float w = expf(logit_w[e] - decf(segmax[sg]));
  logit_w[e] = w;
  atomicAdd(&segsum[sg], w);
}

// hierarchical exclusive scan: part sums -> top scan -> final
__launch_bounds__(256) __global__
void scan_part(const int* __restrict__ cnt, int* __restrict__ bsum, int n){
  int b = blockIdx.x, tid = threadIdx.x;
  int i = b*1024 + tid*4;
  int4 v = make_int4(0,0,0,0);
  if (i + 3 < n) v = *(const int4*)(cnt + i);
  else {
    if (i   < n) v.x = cnt[i];
    if (i+1 < n) v.y = cnt[i+1];
    if (i+2 < n) v.z = cnt[i+2];
    if (i+3 < n) v.w = cnt[i+3];
  }
  int s = v.x+v.y+v.z+v.w;
  int sc = wave_incl_scan(s);
  __shared__ int wsum[4];
  if ((tid & 63) == 63) wsum[tid>>6] = sc;
  __syncthreads();
  if (tid == 0) bsum[b] = wsum[0]+wsum[1]+wsum[2]+wsum[3];
}

__launch_bounds__(128) __global__
void scan_top(int* __restrict__ bsum, int nb){
  int tid = threadIdx.x;
  int v = (tid < nb) ? bsum[tid] : 0;
  int sc = wave_incl_scan(v);
  __shared__ int w0;
  if (tid == 63) w0 = sc;
  __syncthreads();
  if (tid >= 64) sc += w0;
  if (tid < nb) bsum[tid] = sc - v;
}

__launch_bounds__(256) __global__
void scan_final(const int* __restrict__ cnt, const int* __restrict__ boffs,
                int* __restrict__ offs, int n){
  int b = blockIdx.x, tid = threadIdx.x;
  int i = b*1024 + tid*4;
  int4 v = make_int4(0,0,0,0);
  if (i + 3 < n) v = *(const int4*)(cnt + i);
  else {
    if (i   < n) v.x = cnt[i];
    if (i+1 < n) v.y = cnt[i+1];
    if (i+2 < n) v.z = cnt[i+2];
    if (i+3 < n) v.w = cnt[i+3];
  }
  int s = v.x+v.y+v.z+v.w;
  int sc = wave_incl_scan(s);
  __shared__ int wsum[4];
  if ((tid & 63) == 63) wsum[tid>>6] = sc;
  __syncthreads();
  int w = tid >> 6;
  int wbase = 0;
  for (int j = 0; j < w; ++j) wbase += wsum[j];
  int excl = boffs[b] + wbase + sc - s;
  if (i   < n) offs[i]   = excl;
  if (i+1 < n) offs[i+1] = excl + v.x;
  if (i+2 < n) offs[i+2] = excl + v.x + v.y;
  if (i+3 < n) offs[i+3] = excl + v.x + v.y + v.z;
}

__launch_bounds__(256) __global__
void scatter_k(const int* __restrict__ seg, const int* __restrict__ offs,
               int* __restrict__ cursor, int* __restrict__ sorted, int E){
  int e = blockIdx.x*256 + threadIdx.x;
  if (e >= E) return;
  int sg = seg[e];
  int p = atomicAdd(&cursor[sg], 1);
  sorted[offs[sg] + p] = e;
}

// per node: 128 threads, 4 cols/thread, one dwordx4 gather per edge.
#define GET_EDGE(k, a, s) \
  do { if ((k) < MAXE){ a = wa[k]; s = wsrc[k]; } \
       else { int e_ = sorted[base+(k)]; a = wbuf[e_]; s = srcA[e_]; } } while(0)

__launch_bounds__(128) __global__
void node_combine(const float* __restrict__ h1, const float* __restrict__ wbuf,
                  const int* __restrict__ sorted, const int* __restrict__ offs,
                  const int* __restrict__ cnt, const float* __restrict__ segsum,
                  const int* __restrict__ srcA,
                  const float* __restrict__ ht, const float* __restrict__ t_src,
                  const float* __restrict__ gamma, const float* __restrict__ beta,
                  const float* __restrict__ p, const float* __restrict__ pn,
                  float* __restrict__ h2, float* __restrict__ score, int N){
  __shared__ float lds[16];
  __shared__ float wa[MAXE];
  __shared__ int   wsrc[MAXE];
  __shared__ float sinv[NT];
  int n = blockIdx.x, tid = threadIdx.x;
  int col = tid * 4;
  int base = offs[n*NT];
  int c0 = cnt[n*NT], c1 = cnt[n*NT+1], c2 = cnt[n*NT+2];
  int total = c0 + c1 + c2;
  for (int k = tid; k < total && k < MAXE; k += 128){
    int e = sorted[base + k];
    wa[k] = wbuf[e];
    wsrc[k] = srcA[e];
  }
  if (tid < NT) sinv[tid] = 1.f / (segsum[n*NT + tid] + 1e-16f);
  __syncthreads();

  float4 acc[NT];
  #pragma unroll
  for (int t = 0; t < NT; ++t) acc[t] = make_float4(0.f, 0.f, 0.f, 0.f);
  int bounds[4] = {0, c0, c0 + c1, total};
  #pragma unroll
  for (int t = 0; t < NT; ++t){
    int lo = bounds[t], hiB = bounds[t+1];
    int k = lo;
    for (; k + 2 <= hiB; k += 2){
      float a0, a1; int s0, s1;
      GET_EDGE(k,   a0, s0);
      GET_EDGE(k+1, a1, s1);
      float4 v0 = *(const float4*)(h1 + (size_t)s0*D + col);
      float4 v1 = *(const float4*)(h1 + (size_t)s1*D + col);
      acc[t].x += a0*v0.x + a1*v1.x;
      acc[t].y += a0*v0.y + a1*v1.y;
      acc[t].z += a0*v0.z + a1*v1.z;
      acc[t].w += a0*v0.w + a1*v1.w;
    }
    if (k < hiB){
      float a; int s;
      GET_EDGE(k, a, s);
      float4 v = *(const float4*)(h1 + (size_t)s*D + col);
      acc[t].x += a*v.x; acc[t].y += a*v.y;
      acc[t].z += a*v.z; acc[t].w += a*v.w;
    }
    acc[t].x *= sinv[t]; acc[t].y *= sinv[t];
    acc[t].z *= sinv[t]; acc[t].w *= sinv[t];
  }

  float4 ts = *(const float4*)(t_src + col);
  float4 dt = bsum4_128(make_float4(
      acc[0].x*ts.x + acc[0].y*ts.y + acc[0].z*ts.z + acc[0].w*ts.w,
      acc[1].x*ts.x + acc[1].y*ts.y + acc[1].z*ts.z + acc[1].w*ts.w,
      acc[2].x*ts.x + acc[2].y*ts.y + acc[2].z*ts.z + acc[2].w*ts.w, 0.f), lds);
  float htn = ht[n];
  float bl0 = c0 > 0 ? leaky(htn + dt.x) : -1e9f;
  float bl1 = c1 > 0 ? leaky(htn + dt.y) : -1e9f;
  float bl2 = c2 > 0 ? leaky(htn + dt.z) : -1e9f;
  float mx = fmaxf(bl0, fmaxf(bl1, bl2));
  float e0 = expf(bl0 - mx), e1 = expf(bl1 - mx), e2 = expf(bl2 - mx);
  float invs = 1.f / (e0 + e1 + e2);
  float4 o;
  o.x = (e0*acc[0].x + e1*acc[1].x + e2*acc[2].x) * invs;
  o.y = (e0*acc[0].y + e1*acc[1].y + e2*acc[2].y) * invs;
  o.z = (e0*acc[0].z + e1*acc[1].z + e2*acc[2].z) * invs;
  o.w = (e0*acc[0].w + e1*acc[1].w + e2*acc[2].w) * invs;
  float4 s2 = bsum4_128(make_float4(o.x+o.y+o.z+o.w,
                                    o.x*o.x+o.y*o.y+o.z*o.z+o.w*o.w, 0.f, 0.f), lds);
  float mu = s2.x * (1.f/D);
  float var = s2.y * (1.f/D) - mu*mu;
  float r = rsqrtf(var + 1e-5f);
  float4 gm = *(const float4*)(gamma + col);
  float4 bt = *(const float4*)(beta + col);
  float4 g;
  g.x = (o.x - mu)*r*gm.x + bt.x;
  g.y = (o.y - mu)*r*gm.y + bt.y;
  g.z = (o.z - mu)*r*gm.z + bt.z;
  g.w = (o.w - mu)*r*gm.w + bt.w;
  *(float4*)(h2 + (size_t)n*D + col) = g;
  float4 pv = *(const float4*)(p + col);
  float4 s3 = bsum4_128(make_float4(g.x*pv.x + g.y*pv.y + g.z*pv.z + g.w*pv.w,
                                    0.f, 0.f, 0.f), lds);
  if (tid == 0){
    float z = s3.x / (pn[0] + 1e-6f);
    score[n] = 1.f / (1.f + expf(-z));
  }
}

// two-stage exact top-10 (order: score desc, index asc — matches jax.lax.top_k)
__launch_bounds__(256) __global__
void topk_local(const float* __restrict__ score, float* __restrict__ cv,
                int* __restrict__ ci, int N){
  int b = blockIdx.x, tid = threadIdx.x;
  int step = (N + TKB - 1) / TKB;
  int lo = b * step;
  int hi = min(N, lo + step);
  __shared__ float wv[4]; __shared__ int wi[4];
  __shared__ int chosen[KC];
  for (int it = 0; it < KC; ++it){
    float bv = -INFINITY; int bi = 0x7fffffff;
    for (int i = lo + tid; i < hi; i += 256){
      bool skip = false;
      for (int t = 0; t < it; ++t) if (chosen[t] == i) skip = true;
      if (skip) continue;
      float v = score[i];
      if (v > bv || (v == bv && i < bi)){ bv = v; bi = i; }
    }
    for (int o = 32; o > 0; o >>= 1){
      float ov = __shfl_down(bv, o); int oi = __shfl_down(bi, o);
      if (ov > bv || (ov == bv && oi < bi)){ bv = ov; bi = oi; }
    }
    if ((tid & 63) == 0){ wv[tid>>6] = bv; wi[tid>>6] = bi; }
    __syncthreads();
    if (tid == 0){
      for (int w2 = 1; w2 < 4; ++w2)
        if (wv[w2] > wv[0] || (wv[w2] == wv[0] && wi[w2] < wi[0])){ wv[0]=wv[w2]; wi[0]=wi[w2]; }
      chosen[it] = wi[0];
      cv[b*KC + it] = wv[0]; ci[b*KC + it] = wi[0];
    }
    __syncthreads();
  }
}

__launch_bounds__(256) __global__
void topk_merge(const float* __restrict__ cv, const int* __restrict__ ci,
                const float* __restrict__ xy, int* __restrict__ centers,
                float* __restrict__ cpos){
  const int NC = TKB * KC;
  __shared__ float sv[TKB*KC]; __shared__ int si[TKB*KC];
  __shared__ float wv[4]; __shared__ int wi[4]; __shared__ int wp[4];
  __shared__ int chosenpos[KC];
  int tid = threadIdx.x;
  for (int i = tid; i < NC; i += 256){ sv[i] = cv[i]; si[i] = ci[i]; }
  __syncthreads();
  for (int it = 0; it < KC; ++it){
    float bv = -INFINITY; int bi = 0x7fffffff; int bp = -1;
    for (int i = tid; i < NC; i += 256){
      bool skip = false;
      for (int t = 0; t < it; ++t) if (chosenpos[t] == i) skip = true;
      if (skip) continue;
      float v = sv[i];
      if (v > bv || (v == bv && si[i] < bi)){ bv = v; bi = si[i]; bp = i; }
    }
    for (int o = 32; o > 0; o >>= 1){
      float ov = __shfl_down(bv, o); int oi = __shfl_down(bi, o); int op = __shfl_down(bp, o);
      if (ov > bv || (ov == bv && oi < bi)){ bv = ov; bi = oi; bp = op; }
    }
    if ((tid & 63) == 0){ wv[tid>>6] = bv; wi[tid>>6] = bi; wp[tid>>6] = bp; }
    __syncthreads();
    if (tid == 0){
      int bw = 0;
      for (int w2 = 1; w2 < 4; ++w2)
        if (wv[w2] > wv[bw] || (wv[w2] == wv[bw] && wi[w2] < wi[bw])) bw = w2;
      chosenpos[it] = wp[bw];
      centers[it] = wi[bw];
      cpos[it*2+0] = xy[(size_t)wi[bw]*2+0]*2.f - 1.f;
      cpos[it*2+1] = xy[(size_t)wi[bw]*2+1]*2.f - 1.f;
    }
    __syncthreads();
  }
}

// register-accumulator pooling: no LDS RMW chain, 512 blocks, unroll-2.
__launch_bounds__(256) __global__
void pool_kernel(const float* __restrict__ h2, const float* __restrict__ score,
                 const float* __restrict__ xy, const float* __restrict__ cpos,
                 float* __restrict__ xsum, float* __restrict__ denom, int N){
  int tid = threadIdx.x;
  float cpx[KC], cpy[KC];
  #pragma unroll
  for (int k = 0; k < KC; ++k){ cpx[k] = cpos[2*k]; cpy[k] = cpos[2*k+1]; }
  float acc0[KC], acc1[KC];
  #pragma unroll
  for (int k = 0; k < KC; ++k){ acc0[k] = 0.f; acc1[k] = 0.f; }
  float ds = 0.f;
  int stride = gridDim.x;
  for (int n = blockIdx.x; n < N; n += 2*stride){
    int n2 = n + stride;
    float px = xy[2*(size_t)n]*2.f - 1.f, py = xy[2*(size_t)n+1]*2.f - 1.f;
    float sA = score[n];
    float vA0 = h2[(size_t)n*D + tid], vA1 = h2[(size_t)n*D + tid + 256];
    float qx = 0.f, qy = 0.f, sB = 0.f, vB0 = 0.f, vB1 = 0.f;
    bool hasB = n2 < N;
    if (hasB){
      qx = xy[2*(size_t)n2]*2.f - 1.f; qy = xy[2*(size_t)n2+1]*2.f - 1.f;
      sB = score[n2];
      vB0 = h2[(size_t)n2*D + tid]; vB1 = h2[(size_t)n2*D + tid + 256];
    }
    int bestA = 0, bestB = 0;
    float bdA = 3.4e38f, bdB = 3.4e38f;
    #pragma unroll
    for (int k = 0; k < KC; ++k){
      float dax = px - cpx[k], day = py - cpy[k];
      float dA = dax*dax + day*day;
      if (dA < bdA){ bdA = dA; bestA = k; }
      float dbx = qx - cpx[k], dby = qy - cpy[k];
      float dB = dbx*dbx + dby*dby;
      if (dB < bdB){ bdB = dB; bestB = k; }
    }
    float wA0 = sA*vA0, wA1 = sA*vA1;
    float wB0 = hasB ? sB*vB0 : 0.f, wB1 = hasB ? sB*vB1 : 0.f;
    #pragma unroll
    for (int k = 0; k < KC; ++k){
      acc0[k] += (bestA == k) ? wA0 : 0.f;
      acc1[k] += (bestA == k) ? wA1 : 0.f;
      acc0[k] += (hasB && bestB == k) ? wB0 : 0.f;
      acc1[k] += (hasB && bestB == k) ? wB1 : 0.f;
    }
    ds += (bestA == tid) ? sA : 0.f;
    ds += (hasB && bestB == tid) ? sB : 0.f;
  }
  #pragma unroll
  for (int k = 0; k < KC; ++k){
    atomicAdd(&xsum[(size_t)k*D + tid],       acc0[k]);
    atomicAdd(&xsum[(size_t)k*D + tid + 256], acc1[k]);
  }
  if (tid < KC) atomicAdd(&denom[tid], ds);
}

__launch_bounds__(256) __global__
void fin_kernel(const float* __restrict__ xsum, const float* __restrict__ denom,
                float* __restrict__ out){
  int k = blockIdx.x, tid = threadIdx.x;
  float inv = 1.f / (denom[k] + 1e-6f);
  out[(size_t)k*D + tid]       = xsum[(size_t)k*D + tid] * inv;
  out[(size_t)k*D + tid + 256] = xsum[(size_t)k*D + tid + 256] * inv;
}

// ---------- launch ----------

extern "C" void kernel_launch(void* const* d_in, const int* in_sizes, int n_in,
                              void* d_out, int out_size, void* d_ws, size_t ws_size,
                              hipStream_t stream){
  const float* x     = (const float*)d_in[0];
  const int*   ei    = (const int*)d_in[1];
  const int*   ntype = (const int*)d_in[2];
  const float* xy    = (const float*)d_in[4];
  const float* W     = (const float*)d_in[5];
  const float* bias  = (const float*)d_in[6];
  const float* a_src = (const float*)d_in[7];
  const float* a_dst = (const float*)d_in[8];
  const float* t_src = (const float*)d_in[9];
  const float* t_dst = (const float*)d_in[10];
  const float* p     = (const float*)d_in[11];
  const float* gamma = (const float*)d_in[12];
  const float* beta  = (const float*)d_in[13];

  int N = in_sizes[0] / D;
  int E = in_sizes[1] / 2;
  const int* srcA = ei;
  const int* dstA = ei + E;
  int Mpad = ((N + 127) / 128) * 128;

  char* ws = (char*)d_ws;
  size_t off = 0;
  auto alloc = [&](size_t bytes) -> void* {
    void* r = ws + off;
    off += (bytes + 255) & ~(size_t)255;
    return r;
  };
  unsigned short* Ahi = (unsigned short*)alloc((size_t)Mpad*D*2);  // h2 overlays later
  unsigned short* Alo = (unsigned short*)alloc((size_t)Mpad*D*2);
  float*    h1     = (float*)alloc((size_t)N*D*4);
  unsigned short* Wph = (unsigned short*)alloc((size_t)D*D*2);
  unsigned short* Wpl = (unsigned short*)alloc((size_t)D*D*2);
  float*    hs     = (float*)alloc((size_t)N*4);
  float*    hd     = (float*)alloc((size_t)N*4);
  float*    ht     = (float*)alloc((size_t)N*4);
  float*    pn     = (float*)alloc(4);
  float*    wbuf   = (float*)alloc((size_t)E*4);
  int*      seg    = (int*)alloc((size_t)E*4);
  unsigned* segmax = (unsigned*)alloc((size_t)N*NT*4);
  float*    segsum = (float*)alloc((size_t)N*NT*4);
  int*      cnt    = (int*)alloc((size_t)N*NT*4);
  int*      offs   = (int*)alloc((size_t)N*NT*4);
  int*      cursor = (int*)alloc((size_t)N*NT*4);
  int*      bsum   = (int*)alloc(128*4);
  int*      sorted = (int*)alloc((size_t)E*4);
  float*    scoreA = (float*)alloc((size_t)N*4);
  float*    cv     = (float*)alloc(TKB*KC*4);
  int*      ci     = (int*)alloc(TKB*KC*4);
  int*      centers= (int*)alloc(KC*4);
  float*    cpos   = (float*)alloc(KC*2*4);
  float*    xsum   = (float*)alloc((size_t)KC*D*4);
  float*    denom  = (float*)alloc(KC*4);

  hipMemsetAsync(segmax, 0, (size_t)N*NT*4, stream);
  hipMemsetAsync(segsum, 0, (size_t)N*NT*4, stream);
  hipMemsetAsync(cnt,    0, (size_t)N*NT*4, stream);
  hipMemsetAsync(cursor, 0, (size_t)N*NT*4, stream);
  hipMemsetAsync(xsum,   0, (size_t)KC*D*4, stream);
  hipMemsetAsync(denom,  0, (size_t)KC*4, stream);

  ln_kernel<<<N, 256, 0, stream>>>(x, gamma, beta, Ahi, Alo, N);
  wprep<<<64, 256, 0, stream>>>(W, Wph, Wpl);

  dim3 ggrid(Mpad/128, 4);
  gemm_mfma<<<ggrid, 256, 0, stream>>>(Ahi, Alo, Wph, Wpl, bias, h1, N);

  rowdots<<<N, 256, 0, stream>>>(h1, a_src, a_dst, t_dst, hs, hd, ht, N);
  pnorm_kernel<<<1, 256, 0, stream>>>(p, pn);

  int eb = (E + 255)/256;
  edge_logit<<<eb, 256, 0, stream>>>(srcA, dstA, ntype, hd, hs, wbuf, seg, segmax, cnt, E);
  edge_exp<<<eb, 256, 0, stream>>>(wbuf, seg, segmax, segsum, E);

  int nseg = N*NT;
  int nb = (nseg + 1023)/1024;
  scan_part<<<nb, 256, 0, stream>>>(cnt, bsum, nseg);
  scan_top<<<1, 128, 0, stream>>>(bsum, nb);
  scan_final<<<nb, 256, 0, stream>>>(cnt, bsum, offs, nseg);
  scatter_k<<<eb, 256, 0, stream>>>(seg, offs, cursor, sorted, E);

  float* h2 = (float*)Ahi;  // overlay: Ahi/Alo dead after gemm
  node_combine<<<N, 128, 0, stream>>>(h1, wbuf, sorted, offs, cnt, segsum, srcA,
                                      ht, t_src, gamma, beta, p, pn, h2, scoreA, N);

  topk_local<<<TKB, 256, 0, stream>>>(scoreA, cv, ci, N);
  topk_merge<<<1, 256, 0, stream>>>(cv, ci, xy, centers, cpos);
  pool_kernel<<<512, 256, 0, stream>>>(h2, scoreA, xy, cpos, xsum, denom, N);
  fin_kernel<<<KC, 256, 0, stream>>>(xsum, denom, (float*)d_out);
}

// Round 11
// 601.441 us; speedup vs baseline: 2.0639x; 1.0131x over previous
//
#include <hip/hip_runtime.h>
#include <math.h>

#define D 512
#define NT 3
#define KC 10
#define MAXE 128
#define TKB 64

typedef __attribute__((ext_vector_type(8))) short bf16x8;
typedef __attribute__((ext_vector_type(4))) float f32x4;

// ---------- helpers ----------

__device__ __forceinline__ unsigned encf(float f){
  unsigned u = __float_as_uint(f);
  return (u & 0x80000000u) ? ~u : (u | 0x80000000u);
}
__device__ __forceinline__ float decf(unsigned u){
  return (u & 0x80000000u) ? __uint_as_float(u & 0x7fffffffu)
                           : __uint_as_float(~u);
}
__device__ __forceinline__ float leaky(float x){ return x > 0.f ? x : 0.2f * x; }

__device__ __forceinline__ unsigned short f2bf(float f){
  unsigned u = __float_as_uint(f);
  u += 0x7fff + ((u >> 16) & 1);
  return (unsigned short)(u >> 16);
}
__device__ __forceinline__ float bf2f(unsigned short h){
  return __uint_as_float(((unsigned)h) << 16);
}

__device__ __forceinline__ void gload_lds16(const void* g, void* l){
  __builtin_amdgcn_global_load_lds((const __attribute__((address_space(1))) void*)g,
                                   (__attribute__((address_space(3))) void*)l, 16, 0, 0);
}

// block reduce for 256-thread blocks (4 waves of 64)
__device__ __forceinline__ float4 bsum4(float4 v, float* lds){
  for (int o = 32; o > 0; o >>= 1){
    v.x += __shfl_down(v.x, o);
    v.y += __shfl_down(v.y, o);
    v.z += __shfl_down(v.z, o);
    v.w += __shfl_down(v.w, o);
  }
  int w = threadIdx.x >> 6, l = threadIdx.x & 63;
  if (l == 0){ lds[w*4+0]=v.x; lds[w*4+1]=v.y; lds[w*4+2]=v.z; lds[w*4+3]=v.w; }
  __syncthreads();
  float4 r;
  r.x = lds[0]+lds[4]+lds[8]+lds[12];
  r.y = lds[1]+lds[5]+lds[9]+lds[13];
  r.z = lds[2]+lds[6]+lds[10]+lds[14];
  r.w = lds[3]+lds[7]+lds[11]+lds[15];
  __syncthreads();
  return r;
}

// block reduce for 128-thread blocks (2 waves of 64)
__device__ __forceinline__ float4 bsum4_128(float4 v, float* lds){
  for (int o = 32; o > 0; o >>= 1){
    v.x += __shfl_down(v.x, o);
    v.y += __shfl_down(v.y, o);
    v.z += __shfl_down(v.z, o);
    v.w += __shfl_down(v.w, o);
  }
  int w = threadIdx.x >> 6, l = threadIdx.x & 63;
  if (l == 0){ lds[w*4+0]=v.x; lds[w*4+1]=v.y; lds[w*4+2]=v.z; lds[w*4+3]=v.w; }
  __syncthreads();
  float4 r;
  r.x = lds[0]+lds[4];
  r.y = lds[1]+lds[5];
  r.z = lds[2]+lds[6];
  r.w = lds[3]+lds[7];
  __syncthreads();
  return r;
}

__device__ __forceinline__ int wave_incl_scan(int v){
  int lane = threadIdx.x & 63;
  for (int o = 1; o < 64; o <<= 1){
    int t = __shfl_up(v, o);
    if (lane >= o) v += t;
  }
  return v;
}

// ---------- kernels ----------

// LayerNorm -> bf16 hi/lo split (row-major)
__launch_bounds__(256) __global__
void ln_kernel(const float* __restrict__ x, const float* __restrict__ g,
               const float* __restrict__ b, unsigned short* __restrict__ Ahi,
               unsigned short* __restrict__ Alo, int N){
  __shared__ float lds[16];
  int n = blockIdx.x, tid = threadIdx.x;
  float v0 = x[(size_t)n*D + tid], v1 = x[(size_t)n*D + tid + 256];
  float4 s = bsum4(make_float4(v0+v1, v0*v0+v1*v1, 0.f, 0.f), lds);
  float mu = s.x * (1.f/D);
  float var = s.y * (1.f/D) - mu*mu;
  float r = rsqrtf(var + 1e-5f);
  float g0 = (v0-mu)*r*g[tid]     + b[tid];
  float g1 = (v1-mu)*r*g[tid+256] + b[tid+256];
  unsigned short h0 = f2bf(g0), h1v = f2bf(g1);
  Ahi[(size_t)n*D + tid]       = h0;
  Alo[(size_t)n*D + tid]       = f2bf(g0 - bf2f(h0));
  Ahi[(size_t)n*D + tid + 256] = h1v;
  Alo[(size_t)n*D + tid + 256] = f2bf(g1 - bf2f(h1v));
}

// W -> transposed K-chunk packed bf16 hi/lo: Wp[n][kbg] chunk = {W[kbg*8..+8][n]}
__launch_bounds__(256) __global__
void wprep(const float* __restrict__ W, unsigned short* __restrict__ Bh,
           unsigned short* __restrict__ Bl){
  __shared__ float wt[8][512];
  int kbg = blockIdx.x, tid = threadIdx.x;
  for (int i = tid; i < 8*512; i += 256){
    int k = i >> 9, n = i & 511;
    wt[k][n] = W[(size_t)(kbg*8 + k)*512 + n];
  }
  __syncthreads();
  for (int n = tid; n < 512; n += 256){
    bf16x8 hv, lv;
    #pragma unroll
    for (int j = 0; j < 8; ++j){
      float v = wt[j][n];
      unsigned short hh = f2bf(v);
      hv[j] = (short)hh;
      lv[j] = (short)f2bf(v - bf2f(hh));
    }
    size_t cb = ((size_t)n*64 + kbg)*8;
    *(bf16x8*)(Bh + cb) = hv;
    *(bf16x8*)(Bl + cb) = lv;
  }
}

// MFMA GEMM: C[M,512] = A @ W + bias, A=hi+lo bf16, 3-term product.
// 128x128 tile, BK=32, 4 waves (2x2), 4x4 16x16x32 frags/wave.
__launch_bounds__(256) __global__
void gemm_mfma(const unsigned short* __restrict__ Ahi, const unsigned short* __restrict__ Alo,
               const unsigned short* __restrict__ Bph, const unsigned short* __restrict__ Bpl,
               const float* __restrict__ bias, float* __restrict__ C, int M){
  __shared__ unsigned short Ah[128*32], Al[128*32], Bh[128*32], Bl[128*32]; // 4 x 8KB
  int tid = threadIdx.x;
  int row0 = blockIdx.x * 128, col0 = blockIdx.y * 128;
  int w = tid >> 6, lane = tid & 63;
  int wr = w >> 1, wc = w & 1;
  int lr = lane & 15, lg = lane >> 4;
  f32x4 acc[4][4];
  #pragma unroll
  for (int i = 0; i < 4; ++i)
    #pragma unroll
    for (int j = 0; j < 4; ++j)
      acc[i][j] = (f32x4){0.f, 0.f, 0.f, 0.f};

  const size_t arow = (size_t)row0 * D;
  for (int k0 = 0; k0 < D; k0 += 32){
    int k0b = k0 >> 3;
    #pragma unroll
    for (int q = 0; q < 2; ++q){
      int c = q*256 + tid;
      int m = c >> 2, slot = c & 3;
      int kb = slot ^ ((m >> 1) & 3);
      size_t ga = arow + (size_t)m*D + k0 + kb*8;       // element idx (ushort)
      gload_lds16(Ahi + ga, Ah + (size_t)c*8);
      gload_lds16(Alo + ga, Al + (size_t)c*8);
      size_t gb = ((size_t)(col0 + m)*64 + k0b + kb)*8; // chunk idx *8 shorts
      gload_lds16(Bph + gb, Bh + (size_t)c*8);
      gload_lds16(Bpl + gb, Bl + (size_t)c*8);
    }
    __syncthreads();
    bf16x8 afh[4], afl[4], bfh[4], bfl[4];
    #pragma unroll
    for (int f = 0; f < 4; ++f){
      int m = wr*64 + f*16 + lr;
      int sA = lg ^ ((m >> 1) & 3);
      afh[f] = *(const bf16x8*)(Ah + (size_t)(m*4 + sA)*8);
      afl[f] = *(const bf16x8*)(Al + (size_t)(m*4 + sA)*8);
      int nn = wc*64 + f*16 + lr;
      int sB = lg ^ ((nn >> 1) & 3);
      bfh[f] = *(const bf16x8*)(Bh + (size_t)(nn*4 + sB)*8);
      bfl[f] = *(const bf16x8*)(Bl + (size_t)(nn*4 + sB)*8);
    }
    #pragma unroll
    for (int i = 0; i < 4; ++i)
      #pragma unroll
      for (int j = 0; j < 4; ++j){
        acc[i][j] = __builtin_amdgcn_mfma_f32_16x16x32_bf16(afh[i], bfh[j], acc[i][j], 0, 0, 0);
        acc[i][j] = __builtin_amdgcn_mfma_f32_16x16x32_bf16(afh[i], bfl[j], acc[i][j], 0, 0, 0);
        acc[i][j] = __builtin_amdgcn_mfma_f32_16x16x32_bf16(afl[i], bfh[j], acc[i][j], 0, 0, 0);
      }
    __syncthreads();
  }
  #pragma unroll
  for (int j = 0; j < 4; ++j){
    int col = col0 + wc*64 + j*16 + lr;
    float bv = bias[col];
    #pragma unroll
    for (int i = 0; i < 4; ++i){
      int rbase = row0 + wr*64 + i*16 + lg*4;
      #pragma unroll
      for (int r = 0; r < 4; ++r){
        int rr = rbase + r;
        if (rr < M) C[(size_t)rr*D + col] = acc[i][j][r] + bv;
      }
    }
  }
}

// per-row dots of h1 with a_src, a_dst, t_dst
__launch_bounds__(256) __global__
void rowdots(const float* __restrict__ h1, const float* __restrict__ a_src,
             const float* __restrict__ a_dst, const float* __restrict__ t_dst,
             float* __restrict__ hs, float* __restrict__ hd, float* __restrict__ ht,
             int N){
  __shared__ float lds[16];
  int n = blockIdx.x, tid = threadIdx.x;
  float v0 = h1[(size_t)n*D + tid], v1 = h1[(size_t)n*D + tid + 256];
  float4 s = bsum4(make_float4(v0*a_src[tid] + v1*a_src[tid+256],
                               v0*a_dst[tid] + v1*a_dst[tid+256],
                               v0*t_dst[tid] + v1*t_dst[tid+256], 0.f), lds);
  if (tid == 0){ hs[n] = s.x; hd[n] = s.y; ht[n] = s.z; }
}

__launch_bounds__(256) __global__
void pnorm_kernel(const float* __restrict__ p, float* __restrict__ pn){
  __shared__ float lds[16];
  int tid = threadIdx.x;
  float v0 = p[tid], v1 = p[tid+256];
  float4 s = bsum4(make_float4(v0*v0 + v1*v1, 0.f, 0.f, 0.f), lds);
  if (tid == 0) pn[0] = sqrtf(s.x);
}

__launch_bounds__(256) __global__
void edge_logit(const int* __restrict__ src, const int* __restrict__ dst,
                const int* __restrict__ ntype,
                const float* __restrict__ hd, const float* __restrict__ hs,
                float* __restrict__ logit, int* __restrict__ seg,
                unsigned* __restrict__ segmax, int* __restrict__ cnt, int E){
  int e = blockIdx.x*256 + threadIdx.x;
  if (e >= E) return;
  int s = src[e], d = dst[e];
  float l = leaky(hd[d] + hs[s]);
  int sg = d*NT + ntype[s];
  logit[e] = l;
  seg[e] = sg;
  atomicMax(&segmax[sg], encf(l));
  atomicAdd(&cnt[sg], 1);
}

// hierarchical exclusive scan: part sums -> top scan -> final
__launch_bounds__(256) __global__
void scan_part(const int* __restrict__ cnt, int* __restrict__ bsum, int n){
  int b = blockIdx.x, tid = threadIdx.x;
  int i = b*1024 + tid*4;
  int4 v = make_int4(0,0,0,0);
  if (i + 3 < n) v = *(const int4*)(cnt + i);
  else {
    if (i   < n) v.x = cnt[i];
    if (i+1 < n) v.y = cnt[i+1];
    if (i+2 < n) v.z = cnt[i+2];
    if (i+3 < n) v.w = cnt[i+3];
  }
  int s = v.x+v.y+v.z+v.w;
  int sc = wave_incl_scan(s);
  __shared__ int wsum[4];
  if ((tid & 63) == 63) wsum[tid>>6] = sc;
  __syncthreads();
  if (tid == 0) bsum[b] = wsum[0]+wsum[1]+wsum[2]+wsum[3];
}

__launch_bounds__(128) __global__
void scan_top(int* __restrict__ bsum, int nb){
  int tid = threadIdx.x;
  int v = (tid < nb) ? bsum[tid] : 0;
  int sc = wave_incl_scan(v);
  __shared__ int w0;
  if (tid == 63) w0 = sc;
  __syncthreads();
  if (tid >= 64) sc += w0;
  if (tid < nb) bsum[tid] = sc - v;
}

__launch_bounds__(256) __global__
void scan_final(const int* __restrict__ cnt, const int* __restrict__ boffs,
                int* __restrict__ offs, int n){
  int b = blockIdx.x, tid = threadIdx.x;
  int i = b*1024 + tid*4;
  int4 v = make_int4(0,0,0,0);
  if (i + 3 < n) v = *(const int4*)(cnt + i);
  else {
    if (i   < n) v.x = cnt[i];
    if (i+1 < n) v.y = cnt[i+1];
    if (i+2 < n) v.z = cnt[i+2];
    if (i+3 < n) v.w = cnt[i+3];
  }
  int s = v.x+v.y+v.z+v.w;
  int sc = wave_incl_scan(s);
  __shared__ int wsum[4];
  if ((tid & 63) == 63) wsum[tid>>6] = sc;
  __syncthreads();
  int w = tid >> 6;
  int wbase = 0;
  for (int j = 0; j < w; ++j) wbase += wsum[j];
  int excl = boffs[b] + wbase + sc - s;
  if (i   < n) offs[i]   = excl;
  if (i+1 < n) offs[i+1] = excl + v.x;
  if (i+2 < n) offs[i+2] = excl + v.x + v.y;
  if (i+3 < n) offs[i+3] = excl + v.x + v.y + v.z;
}

// fused: exp-weight + segment-sum + counting-sort scatter (one E-pass saved)
__launch_bounds__(256) __global__
void scatter_exp(const int* __restrict__ seg, const int* __restrict__ offs,
                 int* __restrict__ cursor, int* __restrict__ sorted,
                 float* __restrict__ wbuf, const unsigned* __restrict__ segmax,
                 float* __restrict__ segsum, int E){
  int e = blockIdx.x*256 + threadIdx.x;
  if (e >= E) return;
  int sg = seg[e];
  float w = expf(wbuf[e] - decf(segmax[sg]));
  wbuf[e] = w;
  atomicAdd(&segsum[sg], w);
  int p = atomicAdd(&cursor[sg], 1);
  sorted[offs[sg] + p] = e;
}

// per node: 128 threads, 4 cols/thread, unroll-4 edge gather (4 dwordx4 in flight).
#define GET_EDGE(k, a, s) \
  do { if ((k) < MAXE){ a = wa[k]; s = wsrc[k]; } \
       else { int e_ = sorted[base+(k)]; a = wbuf[e_]; s = srcA[e_]; } } while(0)

__launch_bounds__(128) __global__
void node_combine(const float* __restrict__ h1, const float* __restrict__ wbuf,
                  const int* __restrict__ sorted, const int* __restrict__ offs,
                  const int* __restrict__ cnt, const float* __restrict__ segsum,
                  const int* __restrict__ srcA,
                  const float* __restrict__ ht, const float* __restrict__ t_src,
                  const float* __restrict__ gamma, const float* __restrict__ beta,
                  const float* __restrict__ p, const float* __restrict__ pn,
                  float* __restrict__ h2, float* __restrict__ score, int N){
  __shared__ float lds[16];
  __shared__ float wa[MAXE];
  __shared__ int   wsrc[MAXE];
  __shared__ float sinv[NT];
  int n = blockIdx.x, tid = threadIdx.x;
  int col = tid * 4;
  int base = offs[n*NT];
  int c0 = cnt[n*NT], c1 = cnt[n*NT+1], c2 = cnt[n*NT+2];
  int total = c0 + c1 + c2;
  for (int k = tid; k < total && k < MAXE; k += 128){
    int e = sorted[base + k];
    wa[k] = wbuf[e];
    wsrc[k] = srcA[e];
  }
  if (tid < NT) sinv[tid] = 1.f / (segsum[n*NT + tid] + 1e-16f);
  __syncthreads();

  float4 acc[NT];
  #pragma unroll
  for (int t = 0; t < NT; ++t) acc[t] = make_float4(0.f, 0.f, 0.f, 0.f);
  int bounds[4] = {0, c0, c0 + c1, total};
  #pragma unroll
  for (int t = 0; t < NT; ++t){
    int lo = bounds[t], hiB = bounds[t+1];
    int k = lo;
    for (; k + 4 <= hiB; k += 4){
      float a0, a1, a2, a3; int s0, s1, s2, s3;
      GET_EDGE(k,   a0, s0);
      GET_EDGE(k+1, a1, s1);
      GET_EDGE(k+2, a2, s2);
      GET_EDGE(k+3, a3, s3);
      float4 v0 = *(const float4*)(h1 + (size_t)s0*D + col);
      float4 v1 = *(const float4*)(h1 + (size_t)s1*D + col);
      float4 v2 = *(const float4*)(h1 + (size_t)s2*D + col);
      float4 v3 = *(const float4*)(h1 + (size_t)s3*D + col);
      acc[t].x += a0*v0.x + a1*v1.x + a2*v2.x + a3*v3.x;
      acc[t].y += a0*v0.y + a1*v1.y + a2*v2.y + a3*v3.y;
      acc[t].z += a0*v0.z + a1*v1.z + a2*v2.z + a3*v3.z;
      acc[t].w += a0*v0.w + a1*v1.w + a2*v2.w + a3*v3.w;
    }
    for (; k < hiB; ++k){
      float a; int s;
      GET_EDGE(k, a, s);
      float4 v = *(const float4*)(h1 + (size_t)s*D + col);
      acc[t].x += a*v.x; acc[t].y += a*v.y;
      acc[t].z += a*v.z; acc[t].w += a*v.w;
    }
    acc[t].x *= sinv[t]; acc[t].y *= sinv[t];
    acc[t].z *= sinv[t]; acc[t].w *= sinv[t];
  }

  float4 ts = *(const float4*)(t_src + col);
  float4 dt = bsum4_128(make_float4(
      acc[0].x*ts.x + acc[0].y*ts.y + acc[0].z*ts.z + acc[0].w*ts.w,
      acc[1].x*ts.x + acc[1].y*ts.y + acc[1].z*ts.z + acc[1].w*ts.w,
      acc[2].x*ts.x + acc[2].y*ts.y + acc[2].z*ts.z + acc[2].w*ts.w, 0.f), lds);
  float htn = ht[n];
  float bl0 = c0 > 0 ? leaky(htn + dt.x) : -1e9f;
  float bl1 = c1 > 0 ? leaky(htn + dt.y) : -1e9f;
  float bl2 = c2 > 0 ? leaky(htn + dt.z) : -1e9f;
  float mx = fmaxf(bl0, fmaxf(bl1, bl2));
  float e0 = expf(bl0 - mx), e1 = expf(bl1 - mx), e2 = expf(bl2 - mx);
  float invs = 1.f / (e0 + e1 + e2);
  float4 o;
  o.x = (e0*acc[0].x + e1*acc[1].x + e2*acc[2].x) * invs;
  o.y = (e0*acc[0].y + e1*acc[1].y + e2*acc[2].y) * invs;
  o.z = (e0*acc[0].z + e1*acc[1].z + e2*acc[2].z) * invs;
  o.w = (e0*acc[0].w + e1*acc[1].w + e2*acc[2].w) * invs;
  float4 s2 = bsum4_128(make_float4(o.x+o.y+o.z+o.w,
                                    o.x*o.x+o.y*o.y+o.z*o.z+o.w*o.w, 0.f, 0.f), lds);
  float mu = s2.x * (1.f/D);
  float var = s2.y * (1.f/D) - mu*mu;
  float r = rsqrtf(var + 1e-5f);
  float4 gm = *(const float4*)(gamma + col);
  float4 bt = *(const float4*)(beta + col);
  float4 g;
  g.x = (o.x - mu)*r*gm.x + bt.x;
  g.y = (o.y - mu)*r*gm.y + bt.y;
  g.z = (o.z - mu)*r*gm.z + bt.z;
  g.w = (o.w - mu)*r*gm.w + bt.w;
  *(float4*)(h2 + (size_t)n*D + col) = g;
  float4 pv = *(const float4*)(p + col);
  float4 s3 = bsum4_128(make_float4(g.x*pv.x + g.y*pv.y + g.z*pv.z + g.w*pv.w,
                                    0.f, 0.f, 0.f), lds);
  if (tid == 0){
    float z = s3.x / (pn[0] + 1e-6f);
    score[n] = 1.f / (1.f + expf(-z));
  }
}

// two-stage exact top-10 (order: score desc, index asc — matches jax.lax.top_k)
__launch_bounds__(256) __global__
void topk_local(const float* __restrict__ score, float* __restrict__ cv,
                int* __restrict__ ci, int N){
  int b = blockIdx.x, tid = threadIdx.x;
  int step = (N + TKB - 1) / TKB;
  int lo = b * step;
  int hi = min(N, lo + step);
  __shared__ float wv[4]; __shared__ int wi[4];
  __shared__ int chosen[KC];
  for (int it = 0; it < KC; ++it){
    float bv = -INFINITY; int bi = 0x7fffffff;
    for (int i = lo + tid; i < hi; i += 256){
      bool skip = false;
      for (int t = 0; t < it; ++t) if (chosen[t] == i) skip = true;
      if (skip) continue;
      float v = score[i];
      if (v > bv || (v == bv && i < bi)){ bv = v; bi = i; }
    }
    for (int o = 32; o > 0; o >>= 1){
      float ov = __shfl_down(bv, o); int oi = __shfl_down(bi, o);
      if (ov > bv || (ov == bv && oi < bi)){ bv = ov; bi = oi; }
    }
    if ((tid & 63) == 0){ wv[tid>>6] = bv; wi[tid>>6] = bi; }
    __syncthreads();
    if (tid == 0){
      for (int w2 = 1; w2 < 4; ++w2)
        if (wv[w2] > wv[0] || (wv[w2] == wv[0] && wi[w2] < wi[0])){ wv[0]=wv[w2]; wi[0]=wi[w2]; }
      chosen[it] = wi[0];
      cv[b*KC + it] = wv[0]; ci[b*KC + it] = wi[0];
    }
    __syncthreads();
  }
}

__launch_bounds__(256) __global__
void topk_merge(const float* __restrict__ cv, const int* __restrict__ ci,
                const float* __restrict__ xy, int* __restrict__ centers,
                float* __restrict__ cpos){
  const int NC = TKB * KC;
  __shared__ float sv[TKB*KC]; __shared__ int si[TKB*KC];
  __shared__ float wv[4]; __shared__ int wi[4]; __shared__ int wp[4];
  __shared__ int chosenpos[KC];
  int tid = threadIdx.x;
  for (int i = tid; i < NC; i += 256){ sv[i] = cv[i]; si[i] = ci[i]; }
  __syncthreads();
  for (int it = 0; it < KC; ++it){
    float bv = -INFINITY; int bi = 0x7fffffff; int bp = -1;
    for (int i = tid; i < NC; i += 256){
      bool skip = false;
      for (int t = 0; t < it; ++t) if (chosenpos[t] == i) skip = true;
      if (skip) continue;
      float v = sv[i];
      if (v > bv || (v == bv && si[i] < bi)){ bv = v; bi = si[i]; bp = i; }
    }
    for (int o = 32; o > 0; o >>= 1){
      float ov = __shfl_down(bv, o); int oi = __shfl_down(bi, o); int op = __shfl_down(bp, o);
      if (ov > bv || (ov == bv && oi < bi)){ bv = ov; bi = oi; bp = op; }
    }
    if ((tid & 63) == 0){ wv[tid>>6] = bv; wi[tid>>6] = bi; wp[tid>>6] = bp; }
    __syncthreads();
    if (tid == 0){
      int bw = 0;
      for (int w2 = 1; w2 < 4; ++w2)
        if (wv[w2] > wv[bw] || (wv[w2] == wv[bw] && wi[w2] < wi[bw])) bw = w2;
      chosenpos[it] = wp[bw];
      centers[it] = wi[bw];
      cpos[it*2+0] = xy[(size_t)wi[bw]*2+0]*2.f - 1.f;
      cpos[it*2+1] = xy[(size_t)wi[bw]*2+1]*2.f - 1.f;
    }
    __syncthreads();
  }
}

// register-accumulator pooling: no LDS RMW chain, 512 blocks, unroll-2.
__launch_bounds__(256) __global__
void pool_kernel(const float* __restrict__ h2, const float* __restrict__ score,
                 const float* __restrict__ xy, const float* __restrict__ cpos,
                 float* __restrict__ xsum, float* __restrict__ denom, int N){
  int tid = threadIdx.x;
  float cpx[KC], cpy[KC];
  #pragma unroll
  for (int k = 0; k < KC; ++k){ cpx[k] = cpos[2*k]; cpy[k] = cpos[2*k+1]; }
  float acc0[KC], acc1[KC];
  #pragma unroll
  for (int k = 0; k < KC; ++k){ acc0[k] = 0.f; acc1[k] = 0.f; }
  float ds = 0.f;
  int stride = gridDim.x;
  for (int n = blockIdx.x; n < N; n += 2*stride){
    int n2 = n + stride;
    float px = xy[2*(size_t)n]*2.f - 1.f, py = xy[2*(size_t)n+1]*2.f - 1.f;
    float sA = score[n];
    float vA0 = h2[(size_t)n*D + tid], vA1 = h2[(size_t)n*D + tid + 256];
    float qx = 0.f, qy = 0.f, sB = 0.f, vB0 = 0.f, vB1 = 0.f;
    bool hasB = n2 < N;
    if (hasB){
      qx = xy[2*(size_t)n2]*2.f - 1.f; qy = xy[2*(size_t)n2+1]*2.f - 1.f;
      sB = score[n2];
      vB0 = h2[(size_t)n2*D + tid]; vB1 = h2[(size_t)n2*D + tid + 256];
    }
    int bestA = 0, bestB = 0;
    float bdA = 3.4e38f, bdB = 3.4e38f;
    #pragma unroll
    for (int k = 0; k < KC; ++k){
      float dax = px - cpx[k], day = py - cpy[k];
      float dA = dax*dax + day*day;
      if (dA < bdA){ bdA = dA; bestA = k; }
      float dbx = qx - cpx[k], dby = qy - cpy[k];
      float dB = dbx*dbx + dby*dby;
      if (dB < bdB){ bdB = dB; bestB = k; }
    }
    float wA0 = sA*vA0, wA1 = sA*vA1;
    float wB0 = hasB ? sB*vB0 : 0.f, wB1 = hasB ? sB*vB1 : 0.f;
    #pragma unroll
    for (int k = 0; k < KC; ++k){
      acc0[k] += (bestA == k) ? wA0 : 0.f;
      acc1[k] += (bestA == k) ? wA1 : 0.f;
      acc0[k] += (hasB && bestB == k) ? wB0 : 0.f;
      acc1[k] += (hasB && bestB == k) ? wB1 : 0.f;
    }
    ds += (bestA == tid) ? sA : 0.f;
    ds += (hasB && bestB == tid) ? sB : 0.f;
  }
  #pragma unroll
  for (int k = 0; k < KC; ++k){
    atomicAdd(&xsum[(size_t)k*D + tid],       acc0[k]);
    atomicAdd(&xsum[(size_t)k*D + tid + 256], acc1[k]);
  }
  if (tid < KC) atomicAdd(&denom[tid], ds);
}

__launch_bounds__(256) __global__
void fin_kernel(const float* __restrict__ xsum, const float* __restrict__ denom,
                float* __restrict__ out){
  int k = blockIdx.x, tid = threadIdx.x;
  float inv = 1.f / (denom[k] + 1e-6f);
  out[(size_t)k*D + tid]       = xsum[(size_t)k*D + tid] * inv;
  out[(size_t)k*D + tid + 256] = xsum[(size_t)k*D + tid + 256] * inv;
}

// ---------- launch ----------

extern "C" void kernel_launch(void* const* d_in, const int* in_sizes, int n_in,
                              void* d_out, int out_size, void* d_ws, size_t ws_size,
                              hipStream_t stream){
  const float* x     = (const float*)d_in[0];
  const int*   ei    = (const int*)d_in[1];
  const int*   ntype = (const int*)d_in[2];
  const float* xy    = (const float*)d_in[4];
  const float* W     = (const float*)d_in[5];
  const float* bias  = (const float*)d_in[6];
  const float* a_src = (const float*)d_in[7];
  const float* a_dst = (const float*)d_in[8];
  const float* t_src = (const float*)d_in[9];
  const float* t_dst = (const float*)d_in[10];
  const float* p     = (const float*)d_in[11];
  const float* gamma = (const float*)d_in[12];
  const float* beta  = (const float*)d_in[13];

  int N = in_sizes[0] / D;
  int E = in_sizes[1] / 2;
  const int* srcA = ei;
  const int* dstA = ei + E;
  int Mpad = ((N + 127) / 128) * 128;

  char* ws = (char*)d_ws;
  size_t off = 0;
  auto alloc = [&](size_t bytes) -> void* {
    void* r = ws + off;
    off += (bytes + 255) & ~(size_t)255;
    return r;
  };
  unsigned short* Ahi = (unsigned short*)alloc((size_t)Mpad*D*2);  // h2 overlays later
  unsigned short* Alo = (unsigned short*)alloc((size_t)Mpad*D*2);
  float*    h1     = (float*)alloc((size_t)N*D*4);
  unsigned short* Wph = (unsigned short*)alloc((size_t)D*D*2);
  unsigned short* Wpl = (unsigned short*)alloc((size_t)D*D*2);
  float*    hs     = (float*)alloc((size_t)N*4);
  float*    hd     = (float*)alloc((size_t)N*4);
  float*    ht     = (float*)alloc((size_t)N*4);
  float*    pn     = (float*)alloc(4);
  float*    wbuf   = (float*)alloc((size_t)E*4);
  int*      seg    = (int*)alloc((size_t)E*4);
  unsigned* segmax = (unsigned*)alloc((size_t)N*NT*4);
  float*    segsum = (float*)alloc((size_t)N*NT*4);
  int*      cnt    = (int*)alloc((size_t)N*NT*4);
  int*      offs   = (int*)alloc((size_t)N*NT*4);
  int*      cursor = (int*)alloc((size_t)N*NT*4);
  int*      bsum   = (int*)alloc(128*4);
  int*      sorted = (int*)alloc((size_t)E*4);
  float*    scoreA = (float*)alloc((size_t)N*4);
  float*    cv     = (float*)alloc(TKB*KC*4);
  int*      ci     = (int*)alloc(TKB*KC*4);
  int*      centers= (int*)alloc(KC*4);
  float*    cpos   = (float*)alloc(KC*2*4);
  float*    xsum   = (float*)alloc((size_t)KC*D*4);
  float*    denom  = (float*)alloc(KC*4);

  hipMemsetAsync(segmax, 0, (size_t)N*NT*4, stream);
  hipMemsetAsync(segsum, 0, (size_t)N*NT*4, stream);
  hipMemsetAsync(cnt,    0, (size_t)N*NT*4, stream);
  hipMemsetAsync(cursor, 0, (size_t)N*NT*4, stream);
  hipMemsetAsync(xsum,   0, (size_t)KC*D*4, stream);
  hipMemsetAsync(denom,  0, (size_t)KC*4, stream);

  ln_kernel<<<N, 256, 0, stream>>>(x, gamma, beta, Ahi, Alo, N);
  wprep<<<64, 256, 0, stream>>>(W, Wph, Wpl);

  dim3 ggrid(Mpad/128, 4);
  gemm_mfma<<<ggrid, 256, 0, stream>>>(Ahi, Alo, Wph, Wpl, bias, h1, N);

  rowdots<<<N, 256, 0, stream>>>(h1, a_src, a_dst, t_dst, hs, hd, ht, N);
  pnorm_kernel<<<1, 256, 0, stream>>>(p, pn);

  int eb = (E + 255)/256;
  edge_logit<<<eb, 256, 0, stream>>>(srcA, dstA, ntype, hd, hs, wbuf, seg, segmax, cnt, E);

  int nseg = N*NT;
  int nb = (nseg + 1023)/1024;
  scan_part<<<nb, 256, 0, stream>>>(cnt, bsum, nseg);
  scan_top<<<1, 128, 0, stream>>>(bsum, nb);
  scan_final<<<nb, 256, 0, stream>>>(cnt, bsum, offs, nseg);
  scatter_exp<<<eb, 256, 0, stream>>>(seg, offs, cursor, sorted, wbuf, segmax, segsum, E);

  float* h2 = (float*)Ahi;  // overlay: Ahi/Alo dead after gemm
  node_combine<<<N, 128, 0, stream>>>(h1, wbuf, sorted, offs, cnt, segsum, srcA,
                                      ht, t_src, gamma, beta, p, pn, h2, scoreA, N);

  topk_local<<<TKB, 256, 0, stream>>>(scoreA, cv, ci, N);
  topk_merge<<<1, 256, 0, stream>>>(cv, ci, xy, centers, cpos);
  pool_kernel<<<512, 256, 0, stream>>>(h2, scoreA, xy, cpos, xsum, denom, N);
  fin_kernel<<<KC, 256, 0, stream>>>(xsum, denom, (float*)d_out);
}